// Round 1
// baseline (1454.883 us; speedup 1.0000x reference)
//
#include <hip/hip_runtime.h>
#include <math.h>

#define N_Q   6273
#define N_KEY 1569
#define NHEAD 12
#define HD    64
#define DIMM  768
#define NSP   6272
#define SCALE 0.125f
#define EPSLN 1e-5f

__device__ __forceinline__ float grp16_max(float v) {
#pragma unroll
    for (int off = 1; off < 16; off <<= 1) v = fmaxf(v, __shfl_xor(v, off, 16));
    return v;
}
__device__ __forceinline__ float grp16_sum(float v) {
#pragma unroll
    for (int off = 1; off < 16; off <<= 1) v += __shfl_xor(v, off, 16);
    return v;
}

// ---------------------------------------------------------------------------
// Generic tiled fp32 GEMM: C[M, Ncols] = A[M,K] @ B[Ncols,K]^T + bias
// MODE 0: plain row-major store to C
// MODE 1: qkv scatter: col j -> which=j/768, head=(j%768)/64, d=j%64
//         dst[(head*N_Q + row)*64 + d]
// ---------------------------------------------------------------------------
template <int MODE>
__global__ __launch_bounds__(256) void gemm_bt(
    const float* __restrict__ A, const float* __restrict__ B,
    const float* __restrict__ bias, int M, int K, int Ncols,
    float* __restrict__ C, float* __restrict__ qd, float* __restrict__ kd,
    float* __restrict__ vd)
{
    __shared__ float As[16][68];
    __shared__ float Bs[16][68];
    const int tid = threadIdx.x;
    const int ty = tid >> 4, tx = tid & 15;
    const int row0 = blockIdx.y * 64;
    const int col0 = blockIdx.x * 64;

    float acc[4][4] = {};

    for (int k0 = 0; k0 < K; k0 += 16) {
#pragma unroll
        for (int i = 0; i < 4; ++i) {
            int e = tid + i * 256;
            int m = e >> 4, kk = e & 15;
            int r = row0 + m;
            As[kk][m] = (r < M) ? A[(size_t)r * K + k0 + kk] : 0.f;
            Bs[kk][m] = B[(size_t)(col0 + m) * K + k0 + kk];
        }
        __syncthreads();
#pragma unroll
        for (int kk = 0; kk < 16; ++kk) {
            float4 a = *(const float4*)&As[kk][ty * 4];
            float4 b = *(const float4*)&Bs[kk][tx * 4];
            float av[4] = {a.x, a.y, a.z, a.w};
            float bv[4] = {b.x, b.y, b.z, b.w};
#pragma unroll
            for (int i = 0; i < 4; ++i)
#pragma unroll
                for (int j = 0; j < 4; ++j) acc[i][j] += av[i] * bv[j];
        }
        __syncthreads();
    }

#pragma unroll
    for (int i = 0; i < 4; ++i) {
        int r = row0 + ty * 4 + i;
        if (r >= M) continue;
#pragma unroll
        for (int j = 0; j < 4; ++j) {
            int c = col0 + tx * 4 + j;
            float val = acc[i][j] + bias[c];
            if (MODE == 0) {
                C[(size_t)r * Ncols + c] = val;
            } else {
                int which = c / DIMM;
                int rem = c - which * DIMM;
                int head = rem >> 6;
                int d = rem & 63;
                float* dst = (which == 0) ? qd : (which == 1) ? kd : vd;
                dst[((size_t)head * N_Q + r) * HD + d] = val;
            }
        }
    }
}

// ---------------------------------------------------------------------------
// Depthwise 3x3x3 pool (stride 1,2,2, pad 1) + LayerNorm over HD.
// One wave per output position (lane = channel). Position 0 = cls (LN only).
// in: [NH][N_Q][HD], wk: [HD][27], out: [NH][N_KEY][HD]
// ---------------------------------------------------------------------------
__global__ __launch_bounds__(256) void pool_ln(
    const float* __restrict__ in, const float* __restrict__ wk,
    const float* __restrict__ g, const float* __restrict__ b,
    float* __restrict__ out)
{
    __shared__ float ws_s[27][64];
    const int tid = threadIdx.x;
    for (int e = tid; e < 27 * 64; e += 256) {
        int d = e / 27, tap = e - d * 27;
        ws_s[tap][d] = wk[e];
    }
    __syncthreads();

    const int wave = tid >> 6, lane = tid & 63;
    const int pos = blockIdx.x * 4 + wave;
    if (pos >= NHEAD * N_KEY) return;
    const int head = pos / N_KEY;
    const int idx = pos - head * N_KEY;
    const float* base = in + (size_t)head * N_Q * HD;

    float val;
    if (idx == 0) {
        val = base[lane];
    } else {
        int p = idx - 1;
        int t1 = p / 196;
        int h1 = (p / 14) % 14;
        int w1 = p % 14;
        val = 0.f;
#pragma unroll
        for (int dt = 0; dt < 3; ++dt) {
            int t = t1 + dt - 1;
            if (t < 0 || t >= 8) continue;
#pragma unroll
            for (int dh = 0; dh < 3; ++dh) {
                int h = 2 * h1 + dh - 1;
                if (h < 0 || h >= 28) continue;
#pragma unroll
                for (int dw = 0; dw < 3; ++dw) {
                    int w = 2 * w1 + dw - 1;
                    if (w < 0 || w >= 28) continue;
                    int n = 1 + (t * 28 + h) * 28 + w;
                    val += base[(size_t)n * HD + lane] * ws_s[(dt * 3 + dh) * 3 + dw][lane];
                }
            }
        }
    }
    // LayerNorm across the 64 lanes
    float mu = val;
#pragma unroll
    for (int off = 1; off < 64; off <<= 1) mu += __shfl_xor(mu, off, 64);
    mu *= (1.f / 64.f);
    float dv = val - mu;
    float var = dv * dv;
#pragma unroll
    for (int off = 1; off < 64; off <<= 1) var += __shfl_xor(var, off, 64);
    var *= (1.f / 64.f);
    out[(size_t)pos * HD + lane] = dv * rsqrtf(var + EPSLN) * g[lane] + b[lane];
}

// ---------------------------------------------------------------------------
// Rel-pos dot tables: for each (head, qs) and each k index, dot(q_row, R[idx]).
// oh: [NH][NSP][14], ow: [NH][NSP][14], ot: [NH][NSP][8]
// ---------------------------------------------------------------------------
__global__ __launch_bounds__(256) void rel_dots(
    const float* __restrict__ q, const float* __restrict__ rh,
    const float* __restrict__ rw, const float* __restrict__ rt,
    float* __restrict__ oh, float* __restrict__ ow, float* __restrict__ ot)
{
    int id = blockIdx.x * 256 + threadIdx.x;
    const int total = NHEAD * NSP * 36;
    if (id >= total) return;
    int j = id % 36;
    int qs = (id / 36) % NSP;
    int head = id / (36 * NSP);
    const float* qrow = q + ((size_t)head * N_Q + 1 + qs) * HD;

    int t = qs / 784, h = (qs / 28) % 28, w = qs % 28;
    const float* R;
    float* O;
    size_t oidx;
    if (j < 14) {
        R = rh + (size_t)(h - 2 * j + 26) * HD;
        O = oh; oidx = ((size_t)head * NSP + qs) * 14 + j;
    } else if (j < 28) {
        int jj = j - 14;
        R = rw + (size_t)(w - 2 * jj + 26) * HD;
        O = ow; oidx = ((size_t)head * NSP + qs) * 14 + jj;
    } else {
        int jj = j - 28;
        R = rt + (size_t)(t - jj + 7) * HD;
        O = ot; oidx = ((size_t)head * NSP + qs) * 8 + jj;
    }
    const float4* q4 = (const float4*)qrow;
    const float4* R4 = (const float4*)R;
    float s = 0.f;
#pragma unroll
    for (int c = 0; c < 16; ++c) {
        float4 a = q4[c], bb = R4[c];
        s += a.x * bb.x + a.y * bb.y + a.z * bb.z + a.w * bb.w;
    }
    O[oidx] = s;
}

// ---------------------------------------------------------------------------
// Fused flash attention. Block = (64-query tile, head). 256 threads, 4x4
// micro-tiles, 64-key tiles, online softmax, rel-pos bias from LDS tables.
// out: [N_Q][DIM]  (cols = head*64 + d) so proj GEMM reads it directly.
// ---------------------------------------------------------------------------
__global__ __launch_bounds__(256) void attn_fused(
    const float* __restrict__ q, const float* __restrict__ kp,
    const float* __restrict__ vp, const float* __restrict__ relh,
    const float* __restrict__ relw, const float* __restrict__ relt,
    float* __restrict__ out)
{
    __shared__ float Qt[64][68];   // [dim][qrow], scaled
    __shared__ float Kt[64][68];   // [dim][key]
    __shared__ float Vs[64][68];   // [key][dim]
    __shared__ float Ps[64][68];   // [qrow][key]
    __shared__ float rh_s[64][14], rw_s[64][14], rt_s[64][8];

    const int tid = threadIdx.x;
    const int ty = tid >> 4, tx = tid & 15;
    const int head = blockIdx.y;
    const int q0 = blockIdx.x * 64;

    // load Q tile transposed, scaled
#pragma unroll
    for (int i = 0; i < 16; ++i) {
        int e = tid + i * 256;
        int r = e >> 6, c = e & 63;
        int gq = q0 + r;
        float v = (gq < N_Q) ? q[((size_t)head * N_Q + gq) * HD + c] * SCALE : 0.f;
        Qt[c][r] = v;
    }
    // load rel-pos bias tables for the 64 query rows
    for (int e = tid; e < 64 * 36; e += 256) {
        int r = e / 36, j = e - r * 36;
        int gq = q0 + r;
        float v = 0.f;
        if (gq >= 1 && gq < N_Q) {
            int qs = gq - 1;
            if (j < 14)      v = relh[((size_t)head * NSP + qs) * 14 + j];
            else if (j < 28) v = relw[((size_t)head * NSP + qs) * 14 + (j - 14)];
            else             v = relt[((size_t)head * NSP + qs) * 8 + (j - 28)];
        }
        if (j < 14)      rh_s[r][j] = v;
        else if (j < 28) rw_s[r][j - 14] = v;
        else             rt_s[r][j - 28] = v;
    }

    float m_run[4], l_run[4], o[4][4];
#pragma unroll
    for (int i = 0; i < 4; ++i) {
        m_run[i] = -1e30f; l_run[i] = 0.f;
#pragma unroll
        for (int j = 0; j < 4; ++j) o[i][j] = 0.f;
    }

    for (int m0 = 0; m0 < N_KEY; m0 += 64) {
        __syncthreads();  // protect Kt/Vs/Ps from previous iteration reads
#pragma unroll
        for (int i = 0; i < 16; ++i) {
            int e = tid + i * 256;
            int r = e >> 6, c = e & 63;
            int gm = m0 + r;
            float kv = 0.f, vv = 0.f;
            if (gm < N_KEY) {
                kv = kp[((size_t)head * N_KEY + gm) * HD + c];
                vv = vp[((size_t)head * N_KEY + gm) * HD + c];
            }
            Kt[c][r] = kv;
            Vs[r][c] = vv;
        }
        __syncthreads();

        // S = Qs @ K^T  (64x64)
        float s[4][4] = {};
#pragma unroll 8
        for (int kk = 0; kk < 64; ++kk) {
            float4 a = *(const float4*)&Qt[kk][ty * 4];
            float4 b = *(const float4*)&Kt[kk][tx * 4];
            float av[4] = {a.x, a.y, a.z, a.w};
            float bv[4] = {b.x, b.y, b.z, b.w};
#pragma unroll
            for (int i = 0; i < 4; ++i)
#pragma unroll
                for (int j = 0; j < 4; ++j) s[i][j] += av[i] * bv[j];
        }

        // bias + key mask
#pragma unroll
        for (int j = 0; j < 4; ++j) {
            int gm = m0 + tx * 4 + j;
            if (gm >= N_KEY) {
#pragma unroll
                for (int i = 0; i < 4; ++i) s[i][j] = -1e30f;
            } else if (gm >= 1) {
                int p = gm - 1;
                int kt = p / 196, kh = (p / 14) % 14, kw = p % 14;
#pragma unroll
                for (int i = 0; i < 4; ++i) {
                    int gq = q0 + ty * 4 + i;
                    if (gq >= 1)
                        s[i][j] += rt_s[ty * 4 + i][kt] + rh_s[ty * 4 + i][kh] +
                                   rw_s[ty * 4 + i][kw];
                }
            }
        }

        // online softmax update
        float corr[4];
#pragma unroll
        for (int i = 0; i < 4; ++i) {
            float rm = fmaxf(fmaxf(s[i][0], s[i][1]), fmaxf(s[i][2], s[i][3]));
            rm = grp16_max(rm);
            float mnew = fmaxf(m_run[i], rm);
            corr[i] = __expf(m_run[i] - mnew);
            float ps = 0.f;
#pragma unroll
            for (int j = 0; j < 4; ++j) {
                s[i][j] = __expf(s[i][j] - mnew);
                ps += s[i][j];
            }
            ps = grp16_sum(ps);
            l_run[i] = l_run[i] * corr[i] + ps;
            m_run[i] = mnew;
        }

        // store P, rescale O
#pragma unroll
        for (int i = 0; i < 4; ++i) {
            *(float4*)&Ps[ty * 4 + i][tx * 4] = make_float4(s[i][0], s[i][1], s[i][2], s[i][3]);
#pragma unroll
            for (int j = 0; j < 4; ++j) o[i][j] *= corr[i];
        }
        __syncthreads();

        // O += P @ V
#pragma unroll 8
        for (int kk = 0; kk < 64; ++kk) {
            float4 b = *(const float4*)&Vs[kk][tx * 4];
            float bv[4] = {b.x, b.y, b.z, b.w};
            float pv[4];
#pragma unroll
            for (int i = 0; i < 4; ++i) pv[i] = Ps[ty * 4 + i][kk];
#pragma unroll
            for (int i = 0; i < 4; ++i)
#pragma unroll
                for (int j = 0; j < 4; ++j) o[i][j] += pv[i] * bv[j];
        }
    }

    // write normalized output
#pragma unroll
    for (int i = 0; i < 4; ++i) {
        int gq = q0 + ty * 4 + i;
        if (gq >= N_Q) continue;
        float inv = 1.f / l_run[i];
#pragma unroll
        for (int j = 0; j < 4; ++j)
            out[(size_t)gq * DIMM + head * HD + tx * 4 + j] = o[i][j] * inv;
    }
}

// ---------------------------------------------------------------------------
extern "C" void kernel_launch(void* const* d_in, const int* in_sizes, int n_in,
                              void* d_out, int out_size, void* d_ws, size_t ws_size,
                              hipStream_t stream)
{
    const float* x      = (const float*)d_in[0];
    const float* qkv_w  = (const float*)d_in[1];
    const float* qkv_b  = (const float*)d_in[2];
    const float* proj_w = (const float*)d_in[3];
    const float* proj_b = (const float*)d_in[4];
    const float* pkw    = (const float*)d_in[5];
    const float* pvw    = (const float*)d_in[6];
    const float* nkg    = (const float*)d_in[7];
    const float* nkb    = (const float*)d_in[8];
    const float* nvg    = (const float*)d_in[9];
    const float* nvb    = (const float*)d_in[10];
    const float* rph    = (const float*)d_in[11];
    const float* rpw    = (const float*)d_in[12];
    const float* rpt    = (const float*)d_in[13];

    float* ws = (float*)d_ws;
    const size_t SZ_QKV = (size_t)NHEAD * N_Q * HD;      // 4,817,664
    const size_t SZ_KV  = (size_t)NHEAD * N_KEY * HD;    // 1,204,992
    const size_t SZ_RHW = (size_t)NHEAD * NSP * 14;      // 1,053,696
    const size_t SZ_RT  = (size_t)NHEAD * NSP * 8;       //   602,112

    float* q    = ws;
    float* kr   = q + SZ_QKV;
    float* vr   = kr + SZ_QKV;
    float* kpo  = vr + SZ_QKV;
    float* vpo  = kpo + SZ_KV;
    float* relh = vpo + SZ_KV;
    float* relw = relh + SZ_RHW;
    float* relt = relw + SZ_RHW;
    float* aout = relt + SZ_RT;
    float* outp = (float*)d_out;

    // 1) qkv = x @ qkv_w^T + b, scattered into q/k/v [NH][N][HD]
    gemm_bt<1><<<dim3(36, 99), 256, 0, stream>>>(x, qkv_w, qkv_b, N_Q, DIMM, 0,
                                                 nullptr, q, kr, vr);
    // 2) pool + LN for k and v
    pool_ln<<<dim3((NHEAD * N_KEY) / 4), 256, 0, stream>>>(kr, pkw, nkg, nkb, kpo);
    pool_ln<<<dim3((NHEAD * N_KEY) / 4), 256, 0, stream>>>(vr, pvw, nvg, nvb, vpo);
    // 3) rel-pos bias tables
    {
        int total = NHEAD * NSP * 36;
        rel_dots<<<dim3((total + 255) / 256), 256, 0, stream>>>(q, rph, rpw, rpt,
                                                                relh, relw, relt);
    }
    // 4) fused attention
    attn_fused<<<dim3(99, NHEAD), 256, 0, stream>>>(q, kpo, vpo, relh, relw, relt, aout);
    // 5) proj
    gemm_bt<0><<<dim3(12, 99), 256, 0, stream>>>(aout, proj_w, proj_b, N_Q, DIMM, DIMM,
                                                 outp, nullptr, nullptr, nullptr);
}

// Round 2
// 453.116 us; speedup vs baseline: 3.2108x; 3.2108x over previous
//
#include <hip/hip_runtime.h>

#define N_Q   6273
#define N_KEY 1569
#define NHEAD 12
#define HD    64
#define DIMM  768
#define NSP   6272
#define SCALE 0.125f
#define EPSLN 1e-5f

typedef __bf16 bf16x8 __attribute__((ext_vector_type(8)));
typedef float  f32x4  __attribute__((ext_vector_type(4)));
typedef unsigned short ushort_t;

__device__ __forceinline__ ushort_t f2bf(float f) {
    union { float f; unsigned u; } v; v.f = f;
    unsigned r = (v.u + 0x7FFFu + ((v.u >> 16) & 1u)) >> 16;
    return (ushort_t)r;
}
__device__ __forceinline__ float bf2f(ushort_t b) {
    union { unsigned u; float f; } v; v.u = ((unsigned)b) << 16;
    return v.f;
}
__device__ __forceinline__ float grp16_max(float v) {
#pragma unroll
    for (int off = 1; off < 16; off <<= 1) v = fmaxf(v, __shfl_xor(v, off, 16));
    return v;
}
__device__ __forceinline__ float grp16_sum(float v) {
#pragma unroll
    for (int off = 1; off < 16; off <<= 1) v += __shfl_xor(v, off, 16);
    return v;
}

// ---------------------------------------------------------------------------
// fp32 -> bf16 conversion, 8 elems/thread
// ---------------------------------------------------------------------------
__global__ __launch_bounds__(256) void cvt_bf16(const float* __restrict__ src,
                                                ushort_t* __restrict__ dst, int n8)
{
    int stride = gridDim.x * 256;
    for (int i = blockIdx.x * 256 + threadIdx.x; i < n8; i += stride) {
        const float4* s4 = (const float4*)src + (size_t)i * 2;
        float4 a = s4[0], b = s4[1];
        uint4 o;
        o.x = (unsigned)f2bf(a.x) | ((unsigned)f2bf(a.y) << 16);
        o.y = (unsigned)f2bf(a.z) | ((unsigned)f2bf(a.w) << 16);
        o.z = (unsigned)f2bf(b.x) | ((unsigned)f2bf(b.y) << 16);
        o.w = (unsigned)f2bf(b.z) | ((unsigned)f2bf(b.w) << 16);
        *(uint4*)&dst[(size_t)i * 8] = o;
    }
}

// ---------------------------------------------------------------------------
// bf16 MFMA GEMM: C[M,*] = A[M,K] @ B[Ncols,K]^T + bias. 64x64 tile, BK=128.
// MODE 0: fp32 row-major store (width DIMM). MODE 1: qkv scatter to bf16.
// ---------------------------------------------------------------------------
template <int MODE>
__global__ __launch_bounds__(256) void gemm_mfma(
    const ushort_t* __restrict__ A, const ushort_t* __restrict__ B,
    const float* __restrict__ bias, int M, int K,
    float* __restrict__ Cf, ushort_t* __restrict__ qd, ushort_t* __restrict__ kd,
    ushort_t* __restrict__ vd)
{
    __shared__ ushort_t As[64][136];
    __shared__ ushort_t Bs[64][136];
    const int tid = threadIdx.x;
    const int wave = tid >> 6, lane = tid & 63;
    const int lo = lane & 15, hi = lane >> 4;
    const int row0 = blockIdx.y * 64, col0 = blockIdx.x * 64;

    f32x4 acc[4];
#pragma unroll
    for (int s = 0; s < 4; ++s)
#pragma unroll
        for (int r = 0; r < 4; ++r) acc[s][r] = 0.f;

    for (int k0 = 0; k0 < K; k0 += 128) {
        __syncthreads();
#pragma unroll
        for (int i = 0; i < 4; ++i) {
            int c = tid + i * 256;
            int r = c >> 4, cg = c & 15;
            int gr = row0 + r;
            uint4 va = make_uint4(0, 0, 0, 0);
            if (gr < M) va = *(const uint4*)&A[(size_t)gr * K + k0 + cg * 8];
            *(uint4*)&As[r][cg * 8] = va;
            uint4 vb = *(const uint4*)&B[(size_t)(col0 + r) * K + k0 + cg * 8];
            *(uint4*)&Bs[r][cg * 8] = vb;
        }
        __syncthreads();
#pragma unroll
        for (int ks = 0; ks < 4; ++ks) {
            bf16x8 a = *(const bf16x8*)&As[wave * 16 + lo][ks * 32 + hi * 8];
#pragma unroll
            for (int sub = 0; sub < 4; ++sub) {
                bf16x8 b = *(const bf16x8*)&Bs[sub * 16 + lo][ks * 32 + hi * 8];
                acc[sub] = __builtin_amdgcn_mfma_f32_16x16x32_bf16(a, b, acc[sub], 0, 0, 0);
            }
        }
    }

#pragma unroll
    for (int sub = 0; sub < 4; ++sub) {
#pragma unroll
        for (int reg = 0; reg < 4; ++reg) {
            int r = row0 + wave * 16 + hi * 4 + reg;
            if (r >= M) continue;
            int ccol = col0 + sub * 16 + lo;
            float val = acc[sub][reg] + bias[ccol];
            if (MODE == 0) {
                Cf[(size_t)r * DIMM + ccol] = val;
            } else {
                int which = ccol / DIMM;
                int rem = ccol - which * DIMM;
                int head = rem >> 6, d = rem & 63;
                ushort_t* dst = (which == 0) ? qd : (which == 1) ? kd : vd;
                dst[((size_t)head * N_Q + r) * HD + d] = f2bf(val);
            }
        }
    }
}

// ---------------------------------------------------------------------------
// Depthwise 3x3x3 pool (stride 1,2,2, pad 1) + LayerNorm over HD. bf16 in/out.
// ---------------------------------------------------------------------------
__global__ __launch_bounds__(256) void pool_ln(
    const ushort_t* __restrict__ in, const float* __restrict__ wk,
    const float* __restrict__ g, const float* __restrict__ b,
    ushort_t* __restrict__ out)
{
    __shared__ float ws_s[27][64];
    const int tid = threadIdx.x;
    for (int e = tid; e < 27 * 64; e += 256) {
        int d = e / 27, tap = e - d * 27;
        ws_s[tap][d] = wk[e];
    }
    __syncthreads();

    const int wave = tid >> 6, lane = tid & 63;
    const int pos = blockIdx.x * 4 + wave;
    if (pos >= NHEAD * N_KEY) return;
    const int head = pos / N_KEY;
    const int idx = pos - head * N_KEY;
    const ushort_t* base = in + (size_t)head * N_Q * HD;

    float val;
    if (idx == 0) {
        val = bf2f(base[lane]);
    } else {
        int p = idx - 1;
        int t1 = p / 196;
        int h1 = (p / 14) % 14;
        int w1 = p % 14;
        val = 0.f;
#pragma unroll
        for (int dt = 0; dt < 3; ++dt) {
            int t = t1 + dt - 1;
            if (t < 0 || t >= 8) continue;
#pragma unroll
            for (int dh = 0; dh < 3; ++dh) {
                int h = 2 * h1 + dh - 1;
                if (h < 0 || h >= 28) continue;
#pragma unroll
                for (int dw = 0; dw < 3; ++dw) {
                    int w = 2 * w1 + dw - 1;
                    if (w < 0 || w >= 28) continue;
                    int n = 1 + (t * 28 + h) * 28 + w;
                    val += bf2f(base[(size_t)n * HD + lane]) * ws_s[(dt * 3 + dh) * 3 + dw][lane];
                }
            }
        }
    }
    float mu = val;
#pragma unroll
    for (int off = 1; off < 64; off <<= 1) mu += __shfl_xor(mu, off, 64);
    mu *= (1.f / 64.f);
    float dv = val - mu;
    float var = dv * dv;
#pragma unroll
    for (int off = 1; off < 64; off <<= 1) var += __shfl_xor(var, off, 64);
    var *= (1.f / 64.f);
    out[(size_t)pos * HD + lane] = f2bf(dv * rsqrtf(var + EPSLN) * g[lane] + b[lane]);
}

// ---------------------------------------------------------------------------
// Rel-pos dot tables (q in bf16, tables fp32)
// ---------------------------------------------------------------------------
__global__ __launch_bounds__(256) void rel_dots(
    const ushort_t* __restrict__ q, const float* __restrict__ rh,
    const float* __restrict__ rw, const float* __restrict__ rt,
    float* __restrict__ oh, float* __restrict__ ow, float* __restrict__ ot)
{
    int id = blockIdx.x * 256 + threadIdx.x;
    const int total = NHEAD * NSP * 36;
    if (id >= total) return;
    int j = id % 36;
    int qs = (id / 36) % NSP;
    int head = id / (36 * NSP);
    const ushort_t* qrow = q + ((size_t)head * N_Q + 1 + qs) * HD;

    int t = qs / 784, h = (qs / 28) % 28, w = qs % 28;
    const float* R;
    float* O;
    size_t oidx;
    if (j < 14) {
        R = rh + (size_t)(h - 2 * j + 26) * HD;
        O = oh; oidx = ((size_t)head * NSP + qs) * 14 + j;
    } else if (j < 28) {
        int jj = j - 14;
        R = rw + (size_t)(w - 2 * jj + 26) * HD;
        O = ow; oidx = ((size_t)head * NSP + qs) * 14 + jj;
    } else {
        int jj = j - 28;
        R = rt + (size_t)(t - jj + 7) * HD;
        O = ot; oidx = ((size_t)head * NSP + qs) * 8 + jj;
    }
    float s = 0.f;
#pragma unroll
    for (int c = 0; c < 64; c += 4) {
        ushort4 qq = *(const ushort4*)&qrow[c];
        float4 R4 = *(const float4*)&R[c];
        s += bf2f(qq.x) * R4.x + bf2f(qq.y) * R4.y + bf2f(qq.z) * R4.z + bf2f(qq.w) * R4.w;
    }
    O[oidx] = s;
}

// ---------------------------------------------------------------------------
// Fused flash attention with MFMA. Block = (64 q, head), 4 waves.
// Q frags in registers; K row-major LDS; V transposed LDS; P via LDS bf16.
// out: bf16 [N_Q][DIMM]
// ---------------------------------------------------------------------------
__global__ __launch_bounds__(256) void attn_mfma(
    const ushort_t* __restrict__ q, const ushort_t* __restrict__ kp,
    const ushort_t* __restrict__ vp, const float* __restrict__ relh,
    const float* __restrict__ relw, const float* __restrict__ relt,
    ushort_t* __restrict__ aout)
{
    __shared__ ushort_t Ks[64][72];
    __shared__ ushort_t Vt[64][72];
    __shared__ ushort_t Ps[64][72];
    __shared__ float rh_s[64][14], rw_s[64][14], rt_s[64][8];

    const int tid = threadIdx.x;
    const int wave = tid >> 6, lane = tid & 63;
    const int lo = lane & 15, hi = lane >> 4;
    const int head = blockIdx.y;
    const int q0 = blockIdx.x * 64;

    // Q fragments in registers (row = lo within wave's 16-row stripe)
    bf16x8 qa[2];
    {
        int qrow = q0 + wave * 16 + lo;
        if (qrow < N_Q) {
            const ushort_t* qpt = &q[((size_t)head * N_Q + qrow) * HD];
            qa[0] = *(const bf16x8*)&qpt[hi * 8];
            qa[1] = *(const bf16x8*)&qpt[32 + hi * 8];
        } else {
#pragma unroll
            for (int j = 0; j < 8; ++j) { qa[0][j] = (__bf16)0.0f; qa[1][j] = (__bf16)0.0f; }
        }
    }

    // rel-pos bias tables for this q-tile
    for (int e = tid; e < 64 * 36; e += 256) {
        int r = e / 36, j = e - r * 36;
        int gq = q0 + r;
        float v = 0.f;
        if (gq >= 1 && gq < N_Q) {
            int qs = gq - 1;
            if (j < 14)      v = relh[((size_t)head * NSP + qs) * 14 + j];
            else if (j < 28) v = relw[((size_t)head * NSP + qs) * 14 + (j - 14)];
            else             v = relt[((size_t)head * NSP + qs) * 8 + (j - 28)];
        }
        if (j < 14)      rh_s[r][j] = v;
        else if (j < 28) rw_s[r][j - 14] = v;
        else             rt_s[r][j - 28] = v;
    }

    float m_run[4], l_run[4];
    f32x4 o[4];
#pragma unroll
    for (int i = 0; i < 4; ++i) {
        m_run[i] = -1e30f; l_run[i] = 0.f;
#pragma unroll
        for (int r = 0; r < 4; ++r) o[i][r] = 0.f;
    }

    for (int m0 = 0; m0 < N_KEY; m0 += 64) {
        __syncthreads();  // also covers bias-table writes on first iter
        // stage K (row-major), coalesced
#pragma unroll
        for (int i = 0; i < 2; ++i) {
            int c = tid + i * 256;
            int kr = c >> 3, cg = c & 7;
            int gm = m0 + kr;
            uint4 kv = make_uint4(0, 0, 0, 0);
            if (gm < N_KEY) kv = *(const uint4*)&kp[((size_t)head * N_KEY + gm) * HD + cg * 8];
            *(uint4*)&Ks[kr][cg * 8] = kv;
        }
        // stage V transposed (lane = key -> conflict-free 2B writes)
#pragma unroll
        for (int i = 0; i < 2; ++i) {
            int c = tid + i * 256;
            int key = c & 63, d0 = (c >> 6) * 8;
            int gm = m0 + key;
            uint4 vv = make_uint4(0, 0, 0, 0);
            if (gm < N_KEY) vv = *(const uint4*)&vp[((size_t)head * N_KEY + gm) * HD + d0];
            ushort_t tmp[8];
            *(uint4*)tmp = vv;
#pragma unroll
            for (int j = 0; j < 8; ++j) Vt[d0 + j][key] = tmp[j];
        }
        __syncthreads();

        // S = Q @ K^T  (wave's 16 rows x 64 keys)
        f32x4 s[4];
#pragma unroll
        for (int sub = 0; sub < 4; ++sub)
#pragma unroll
            for (int r = 0; r < 4; ++r) s[sub][r] = 0.f;
#pragma unroll
        for (int kh2 = 0; kh2 < 2; ++kh2) {
#pragma unroll
            for (int sub = 0; sub < 4; ++sub) {
                bf16x8 kb = *(const bf16x8*)&Ks[sub * 16 + lo][kh2 * 32 + hi * 8];
                s[sub] = __builtin_amdgcn_mfma_f32_16x16x32_bf16(qa[kh2], kb, s[sub], 0, 0, 0);
            }
        }

        // scale + rel-pos bias + key mask
#pragma unroll
        for (int sub = 0; sub < 4; ++sub) {
            int gm = m0 + sub * 16 + lo;
            if (gm >= N_KEY) {
#pragma unroll
                for (int reg = 0; reg < 4; ++reg) s[sub][reg] = -1e30f;
            } else {
                int p = gm - 1;
                int dt = p / 196, dh = (p / 14) % 14, dw = p % 14;
#pragma unroll
                for (int reg = 0; reg < 4; ++reg) {
                    int rl = wave * 16 + hi * 4 + reg;
                    float v = s[sub][reg] * SCALE;
                    if (gm >= 1 && (q0 + rl) >= 1)
                        v += rt_s[rl][dt] + rh_s[rl][dh] + rw_s[rl][dw];
                    s[sub][reg] = v;
                }
            }
        }

        // online softmax (per owned row; reduce across 16-lane row group)
        float corr[4];
#pragma unroll
        for (int reg = 0; reg < 4; ++reg) {
            float rm = fmaxf(fmaxf(s[0][reg], s[1][reg]), fmaxf(s[2][reg], s[3][reg]));
            rm = grp16_max(rm);
            float mnew = fmaxf(m_run[reg], rm);
            corr[reg] = __expf(m_run[reg] - mnew);
            float ps = 0.f;
#pragma unroll
            for (int sub = 0; sub < 4; ++sub) {
                float pp = __expf(s[sub][reg] - mnew);
                s[sub][reg] = pp; ps += pp;
            }
            ps = grp16_sum(ps);
            l_run[reg] = l_run[reg] * corr[reg] + ps;
            m_run[reg] = mnew;
        }
#pragma unroll
        for (int dsub = 0; dsub < 4; ++dsub)
#pragma unroll
            for (int reg = 0; reg < 4; ++reg) o[dsub][reg] *= corr[reg];

        // P -> LDS bf16 (wave-private rows; no cross-wave barrier needed)
#pragma unroll
        for (int sub = 0; sub < 4; ++sub)
#pragma unroll
            for (int reg = 0; reg < 4; ++reg)
                Ps[wave * 16 + hi * 4 + reg][sub * 16 + lo] = f2bf(s[sub][reg]);

        // O += P @ V
#pragma unroll
        for (int kh2 = 0; kh2 < 2; ++kh2) {
            bf16x8 pa = *(const bf16x8*)&Ps[wave * 16 + lo][kh2 * 32 + hi * 8];
#pragma unroll
            for (int dsub = 0; dsub < 4; ++dsub) {
                bf16x8 vb = *(const bf16x8*)&Vt[dsub * 16 + lo][kh2 * 32 + hi * 8];
                o[dsub] = __builtin_amdgcn_mfma_f32_16x16x32_bf16(pa, vb, o[dsub], 0, 0, 0);
            }
        }
    }

    // epilogue
#pragma unroll
    for (int reg = 0; reg < 4; ++reg) {
        int rl = wave * 16 + hi * 4 + reg;
        int gq = q0 + rl;
        if (gq >= N_Q) continue;
        float inv = 1.f / l_run[reg];
#pragma unroll
        for (int dsub = 0; dsub < 4; ++dsub)
            aout[(size_t)gq * DIMM + head * HD + dsub * 16 + lo] = f2bf(o[dsub][reg] * inv);
    }
}

// ---------------------------------------------------------------------------
extern "C" void kernel_launch(void* const* d_in, const int* in_sizes, int n_in,
                              void* d_out, int out_size, void* d_ws, size_t ws_size,
                              hipStream_t stream)
{
    const float* x      = (const float*)d_in[0];
    const float* qkv_w  = (const float*)d_in[1];
    const float* qkv_b  = (const float*)d_in[2];
    const float* proj_w = (const float*)d_in[3];
    const float* proj_b = (const float*)d_in[4];
    const float* pkw    = (const float*)d_in[5];
    const float* pvw    = (const float*)d_in[6];
    const float* nkg    = (const float*)d_in[7];
    const float* nkb    = (const float*)d_in[8];
    const float* nvg    = (const float*)d_in[9];
    const float* nvb    = (const float*)d_in[10];
    const float* rph    = (const float*)d_in[11];
    const float* rpw    = (const float*)d_in[12];
    const float* rpt    = (const float*)d_in[13];

    const size_t SZ_X     = (size_t)N_Q * DIMM;          // 4,817,664
    const size_t SZ_QKVW  = (size_t)3 * DIMM * DIMM;     // 1,769,472
    const size_t SZ_PROJW = (size_t)DIMM * DIMM;         //   589,824
    const size_t SZ_QKV   = (size_t)NHEAD * N_Q * HD;    // 4,817,664
    const size_t SZ_KV    = (size_t)NHEAD * N_KEY * HD;  // 1,204,992
    const size_t SZ_RHW   = (size_t)NHEAD * NSP * 14;
    const size_t SZ_RT    = (size_t)NHEAD * NSP * 8;

    ushort_t* xb    = (ushort_t*)d_ws;
    ushort_t* qkvwb = xb + SZ_X;
    ushort_t* projwb= qkvwb + SZ_QKVW;
    ushort_t* qb    = projwb + SZ_PROJW;
    ushort_t* kb    = qb + SZ_QKV;
    ushort_t* vb    = kb + SZ_QKV;
    ushort_t* kpo   = vb + SZ_QKV;
    ushort_t* vpo   = kpo + SZ_KV;
    ushort_t* aout  = vpo + SZ_KV;
    float*    relh  = (float*)(aout + SZ_QKV);
    float*    relw  = relh + SZ_RHW;
    float*    relt  = relw + SZ_RHW;
    float*    outp  = (float*)d_out;

    // 0) convert inputs to bf16
    cvt_bf16<<<2048, 256, 0, stream>>>(x, xb, (int)(SZ_X / 8));
    cvt_bf16<<<1024, 256, 0, stream>>>(qkv_w, qkvwb, (int)(SZ_QKVW / 8));
    cvt_bf16<<<512, 256, 0, stream>>>(proj_w, projwb, (int)(SZ_PROJW / 8));

    // 1) qkv GEMM (MFMA), scatter to q/k/v bf16
    gemm_mfma<1><<<dim3(36, 99), 256, 0, stream>>>(xb, qkvwb, qkv_b, N_Q, DIMM,
                                                   nullptr, qb, kb, vb);
    // 2) pool + LN
    pool_ln<<<dim3((NHEAD * N_KEY + 3) / 4), 256, 0, stream>>>(kb, pkw, nkg, nkb, kpo);
    pool_ln<<<dim3((NHEAD * N_KEY + 3) / 4), 256, 0, stream>>>(vb, pvw, nvg, nvb, vpo);
    // 3) rel-pos tables
    {
        int total = NHEAD * NSP * 36;
        rel_dots<<<dim3((total + 255) / 256), 256, 0, stream>>>(qb, rph, rpw, rpt,
                                                                relh, relw, relt);
    }
    // 4) fused attention (MFMA)
    attn_mfma<<<dim3(99, NHEAD), 256, 0, stream>>>(qb, kpo, vpo, relh, relw, relt, aout);
    // 5) proj GEMM (MFMA)
    gemm_mfma<0><<<dim3(12, 99), 256, 0, stream>>>(aout, projwb, proj_b, N_Q, DIMM,
                                                   outp, nullptr, nullptr, nullptr);
}

// Round 3
// 388.135 us; speedup vs baseline: 3.7484x; 1.1674x over previous
//
#include <hip/hip_runtime.h>

#define N_Q   6273
#define N_KEY 1569
#define NHEAD 12
#define HD    64
#define DQH   128     // augmented head dim
#define DIMM  768
#define NSP   6272
#define SCALE 0.125f
#define EPSLN 1e-5f

typedef __bf16 bf16x8 __attribute__((ext_vector_type(8)));
typedef float  f32x4  __attribute__((ext_vector_type(4)));
typedef unsigned short ushort_t;

__device__ __forceinline__ ushort_t f2bf(float f) {
    union { float f; unsigned u; } v; v.f = f;
    unsigned r = (v.u + 0x7FFFu + ((v.u >> 16) & 1u)) >> 16;
    return (ushort_t)r;
}
__device__ __forceinline__ float bf2f(ushort_t b) {
    union { unsigned u; float f; } v; v.u = ((unsigned)b) << 16;
    return v.f;
}
__device__ __forceinline__ float bflo(unsigned u) {
    union { unsigned a; float f; } v; v.a = u << 16; return v.f;
}
__device__ __forceinline__ float bfhi(unsigned u) {
    union { unsigned a; float f; } v; v.a = u & 0xffff0000u; return v.f;
}
__device__ __forceinline__ ushort_t cvt_native(float f) {
    __bf16 h = (__bf16)f;
    return *(ushort_t*)&h;
}
__device__ __forceinline__ float grp16_max(float v) {
#pragma unroll
    for (int off = 1; off < 16; off <<= 1) v = fmaxf(v, __shfl_xor(v, off, 16));
    return v;
}
__device__ __forceinline__ float grp16_sum(float v) {
#pragma unroll
    for (int off = 1; off < 16; off <<= 1) v += __shfl_xor(v, off, 16);
    return v;
}

// ---------------------------------------------------------------------------
// fp32 -> bf16 conversion, 8 elems/thread
// ---------------------------------------------------------------------------
__global__ __launch_bounds__(256) void cvt_bf16(const float* __restrict__ src,
                                                ushort_t* __restrict__ dst, int n8)
{
    int stride = gridDim.x * 256;
    for (int i = blockIdx.x * 256 + threadIdx.x; i < n8; i += stride) {
        const float4* s4 = (const float4*)src + (size_t)i * 2;
        float4 a = s4[0], b = s4[1];
        uint4 o;
        o.x = (unsigned)f2bf(a.x) | ((unsigned)f2bf(a.y) << 16);
        o.y = (unsigned)f2bf(a.z) | ((unsigned)f2bf(a.w) << 16);
        o.z = (unsigned)f2bf(b.x) | ((unsigned)f2bf(b.y) << 16);
        o.w = (unsigned)f2bf(b.z) | ((unsigned)f2bf(b.w) << 16);
        *(uint4*)&dst[(size_t)i * 8] = o;
    }
}

// ---------------------------------------------------------------------------
// bf16 MFMA GEMM: C[M,*] = A[M,K] @ B[Ncols,K]^T + bias. 64x64 tile, BK=128.
// MODE 0: fp32 row-major store (width DIMM).
// MODE 1: qkv scatter; q -> qhat[head][N_Q][128] cols 0..63, value*SCALE, bf16;
//         k,v -> [head][N_Q][64] bf16.
// ---------------------------------------------------------------------------
template <int MODE>
__global__ __launch_bounds__(256) void gemm_mfma(
    const ushort_t* __restrict__ A, const ushort_t* __restrict__ B,
    const float* __restrict__ bias, int M, int K,
    float* __restrict__ Cf, ushort_t* __restrict__ qd, ushort_t* __restrict__ kd,
    ushort_t* __restrict__ vd)
{
    __shared__ ushort_t As[64][136];
    __shared__ ushort_t Bs[64][136];
    const int tid = threadIdx.x;
    const int wave = tid >> 6, lane = tid & 63;
    const int lo = lane & 15, hi = lane >> 4;
    const int row0 = blockIdx.y * 64, col0 = blockIdx.x * 64;

    f32x4 acc[4];
#pragma unroll
    for (int s = 0; s < 4; ++s)
#pragma unroll
        for (int r = 0; r < 4; ++r) acc[s][r] = 0.f;

    for (int k0 = 0; k0 < K; k0 += 128) {
        __syncthreads();
#pragma unroll
        for (int i = 0; i < 4; ++i) {
            int c = tid + i * 256;
            int r = c >> 4, cg = c & 15;
            int gr = row0 + r;
            uint4 va = make_uint4(0, 0, 0, 0);
            if (gr < M) va = *(const uint4*)&A[(size_t)gr * K + k0 + cg * 8];
            *(uint4*)&As[r][cg * 8] = va;
            uint4 vb = *(const uint4*)&B[(size_t)(col0 + r) * K + k0 + cg * 8];
            *(uint4*)&Bs[r][cg * 8] = vb;
        }
        __syncthreads();
#pragma unroll
        for (int ks = 0; ks < 4; ++ks) {
            bf16x8 a = *(const bf16x8*)&As[wave * 16 + lo][ks * 32 + hi * 8];
#pragma unroll
            for (int sub = 0; sub < 4; ++sub) {
                bf16x8 b = *(const bf16x8*)&Bs[sub * 16 + lo][ks * 32 + hi * 8];
                acc[sub] = __builtin_amdgcn_mfma_f32_16x16x32_bf16(a, b, acc[sub], 0, 0, 0);
            }
        }
    }

#pragma unroll
    for (int sub = 0; sub < 4; ++sub) {
#pragma unroll
        for (int reg = 0; reg < 4; ++reg) {
            int r = row0 + wave * 16 + hi * 4 + reg;
            if (r >= M) continue;
            int ccol = col0 + sub * 16 + lo;
            float val = acc[sub][reg] + bias[ccol];
            if (MODE == 0) {
                Cf[(size_t)r * DIMM + ccol] = val;
            } else {
                int which = ccol / DIMM;
                int rem = ccol - which * DIMM;
                int head = rem >> 6, d = rem & 63;
                if (which == 0) {
                    qd[((size_t)head * N_Q + r) * DQH + d] = f2bf(val * SCALE);
                } else {
                    ushort_t* dst = (which == 1) ? kd : vd;
                    dst[((size_t)head * N_Q + r) * HD + d] = f2bf(val);
                }
            }
        }
    }
}

// ---------------------------------------------------------------------------
// Depthwise 3x3x3 pool (stride 1,2,2, pad 1) + LayerNorm over HD. bf16 in/out.
// KMODE 1: write K-hat rows of width 128: [LN k | one-hot(kh,kw,kt) | zeros]
// KMODE 0: write plain 64-wide rows (V path).
// ---------------------------------------------------------------------------
template <int KMODE>
__global__ __launch_bounds__(256) void pool_ln(
    const ushort_t* __restrict__ in, const float* __restrict__ wk,
    const float* __restrict__ g, const float* __restrict__ b,
    ushort_t* __restrict__ out)
{
    __shared__ float ws_s[27][64];
    const int tid = threadIdx.x;
    for (int e = tid; e < 27 * 64; e += 256) {
        int d = e / 27, tap = e - d * 27;
        ws_s[tap][d] = wk[e];
    }
    __syncthreads();

    const int wave = tid >> 6, lane = tid & 63;
    const int pos = blockIdx.x * 4 + wave;
    if (pos >= NHEAD * N_KEY) return;
    const int head = pos / N_KEY;
    const int idx = pos - head * N_KEY;
    const ushort_t* base = in + (size_t)head * N_Q * HD;

    float val;
    if (idx == 0) {
        val = bf2f(base[lane]);
    } else {
        int p = idx - 1;
        int t1 = p / 196;
        int h1 = (p / 14) % 14;
        int w1 = p % 14;
        val = 0.f;
#pragma unroll
        for (int dt = 0; dt < 3; ++dt) {
            int t = t1 + dt - 1;
            if (t < 0 || t >= 8) continue;
#pragma unroll
            for (int dh = 0; dh < 3; ++dh) {
                int h = 2 * h1 + dh - 1;
                if (h < 0 || h >= 28) continue;
#pragma unroll
                for (int dw = 0; dw < 3; ++dw) {
                    int w = 2 * w1 + dw - 1;
                    if (w < 0 || w >= 28) continue;
                    int n = 1 + (t * 28 + h) * 28 + w;
                    val += bf2f(base[(size_t)n * HD + lane]) * ws_s[(dt * 3 + dh) * 3 + dw][lane];
                }
            }
        }
    }
    float mu = val;
#pragma unroll
    for (int off = 1; off < 64; off <<= 1) mu += __shfl_xor(mu, off, 64);
    mu *= (1.f / 64.f);
    float dv = val - mu;
    float var = dv * dv;
#pragma unroll
    for (int off = 1; off < 64; off <<= 1) var += __shfl_xor(var, off, 64);
    var *= (1.f / 64.f);
    float ln = dv * rsqrtf(var + EPSLN) * g[lane] + b[lane];

    if (KMODE == 0) {
        out[(size_t)pos * HD + lane] = f2bf(ln);
    } else {
        out[(size_t)pos * DQH + lane] = f2bf(ln);
        // one-hot rel channels (cols 64..127); zeros for cls and pad
        float oh = 0.f;
        if (idx > 0) {
            int p = idx - 1;
            int kt = p / 196, kh = (p / 14) % 14, kw = p % 14;
            if ((lane < 14 && lane == kh) ||
                (lane >= 14 && lane < 28 && (lane - 14) == kw) ||
                (lane >= 28 && lane < 36 && (lane - 28) == kt))
                oh = 1.f;
        }
        out[(size_t)pos * DQH + 64 + lane] = f2bf(oh);
    }
}

// ---------------------------------------------------------------------------
// Rel-pos dots -> Q-hat cols 64..99 (bf16). R tables staged in LDS (+1 pad).
// Each wave handles 16 (head,qs) rows; lanes 0..35 each compute one 64-dot.
// q read from qhat cols 0..63 (scaled) -> multiply result by 8 to undo SCALE.
// ---------------------------------------------------------------------------
__global__ __launch_bounds__(256) void rel_dots(
    ushort_t* __restrict__ qhat, const float* __restrict__ rh,
    const float* __restrict__ rw, const float* __restrict__ rt)
{
    __shared__ float Rs[125][65];   // rows 0..54 Rh, 55..109 Rw, 110..124 Rt
    const int tid = threadIdx.x;
    for (int e = tid; e < 125 * 64; e += 256) {
        int r = e >> 6, c = e & 63;
        float v = (r < 55) ? rh[r * 64 + c]
                : (r < 110) ? rw[(r - 55) * 64 + c]
                            : rt[(r - 110) * 64 + c];
        Rs[r][c] = v;
    }
    __syncthreads();

    const int wave = tid >> 6, lane = tid & 63;
#pragma unroll 1
    for (int it = 0; it < 16; ++it) {
        int row = blockIdx.x * 64 + wave * 16 + it;   // in [0, NHEAD*NSP)
        int head = row / NSP;
        int qs = row - head * NSP;
        ushort_t* qrow = qhat + ((size_t)head * N_Q + 1 + qs) * DQH;
        int t = qs / 784, h = (qs / 28) % 28, w = qs % 28;
        int ridx;
        if (lane < 14)      ridx = h - 2 * lane + 26;
        else if (lane < 28) ridx = 55 + (w - 2 * (lane - 14) + 26);
        else if (lane < 36) ridx = 110 + (t - (lane - 28) + 7);
        else                ridx = 0;

        float s = 0.f;
#pragma unroll
        for (int cq = 0; cq < 8; ++cq) {
            uint2 qv = *(const uint2*)&qrow[cq * 8];       // broadcast read
            uint2 qv2 = *(const uint2*)&qrow[cq * 8 + 4];
            const float* Rp = &Rs[ridx][cq * 8];
            s += bflo(qv.x) * Rp[0] + bfhi(qv.x) * Rp[1]
               + bflo(qv.y) * Rp[2] + bfhi(qv.y) * Rp[3]
               + bflo(qv2.x) * Rp[4] + bfhi(qv2.x) * Rp[5]
               + bflo(qv2.y) * Rp[6] + bfhi(qv2.y) * Rp[7];
        }
        if (lane < 36) qrow[64 + lane] = f2bf(s * 8.0f);   // undo SCALE
    }
}

// ---------------------------------------------------------------------------
// Zero Q-hat rel channels for cls rows (q=0 of each head)
// ---------------------------------------------------------------------------
__global__ void cls_fix(ushort_t* __restrict__ qhat) {
    int id = blockIdx.x * 256 + threadIdx.x;
    if (id >= NHEAD * 64) return;
    int head = id >> 6, c = id & 63;
    qhat[((size_t)head * N_Q) * DQH + 64 + c] = 0;
}

// ---------------------------------------------------------------------------
// Fused flash attention with MFMA, D=128 augmented (bias folded into QK^T).
// Block = (64 q, head), 4 waves. Q-hat frags in registers; K-hat in LDS;
// V transposed LDS; P via LDS bf16. out: bf16 [N_Q][DIMM]
// ---------------------------------------------------------------------------
__global__ __launch_bounds__(256) void attn_mfma(
    const ushort_t* __restrict__ qhat, const ushort_t* __restrict__ khat,
    const ushort_t* __restrict__ vp, ushort_t* __restrict__ aout)
{
    __shared__ ushort_t Ks[64][136];
    __shared__ ushort_t Vt[64][72];
    __shared__ ushort_t Ps[64][72];

    const int tid = threadIdx.x;
    const int wave = tid >> 6, lane = tid & 63;
    const int lo = lane & 15, hi = lane >> 4;
    const int head = blockIdx.y;
    const int q0 = blockIdx.x * 64;

    // Q-hat fragments (D=128 -> 4 frags)
    bf16x8 qa[4];
    {
        int qrow = q0 + wave * 16 + lo;
        if (qrow < N_Q) {
            const ushort_t* qpt = &qhat[((size_t)head * N_Q + qrow) * DQH];
#pragma unroll
            for (int j = 0; j < 4; ++j) qa[j] = *(const bf16x8*)&qpt[j * 32 + hi * 8];
        } else {
#pragma unroll
            for (int j = 0; j < 4; ++j)
#pragma unroll
                for (int e = 0; e < 8; ++e) qa[j][e] = (__bf16)0.0f;
        }
    }

    float m_run[4], l_run[4];
    f32x4 o[4];
#pragma unroll
    for (int i = 0; i < 4; ++i) {
        m_run[i] = -1e30f; l_run[i] = 0.f;
#pragma unroll
        for (int r = 0; r < 4; ++r) o[i][r] = 0.f;
    }

    for (int m0 = 0; m0 < N_KEY; m0 += 64) {
        __syncthreads();
        // stage K-hat (row-major, 128 cols), coalesced
#pragma unroll
        for (int i = 0; i < 4; ++i) {
            int c = tid + i * 256;
            int kr = c >> 4, cg = c & 15;
            int gm = m0 + kr;
            uint4 kv = make_uint4(0, 0, 0, 0);
            if (gm < N_KEY) kv = *(const uint4*)&khat[((size_t)head * N_KEY + gm) * DQH + cg * 8];
            *(uint4*)&Ks[kr][cg * 8] = kv;
        }
        // stage V transposed
#pragma unroll
        for (int i = 0; i < 2; ++i) {
            int c = tid + i * 256;
            int key = c & 63, d0 = (c >> 6) * 8;
            int gm = m0 + key;
            uint4 vv = make_uint4(0, 0, 0, 0);
            if (gm < N_KEY) vv = *(const uint4*)&vp[((size_t)head * N_KEY + gm) * HD + d0];
            ushort_t tmp[8];
            *(uint4*)tmp = vv;
#pragma unroll
            for (int j = 0; j < 8; ++j) Vt[d0 + j][key] = tmp[j];
        }
        __syncthreads();

        // S = Q-hat @ K-hat^T  (includes scale and rel-pos bias)
        f32x4 s[4];
#pragma unroll
        for (int sub = 0; sub < 4; ++sub)
#pragma unroll
            for (int r = 0; r < 4; ++r) s[sub][r] = 0.f;
#pragma unroll
        for (int kk = 0; kk < 4; ++kk) {
#pragma unroll
            for (int sub = 0; sub < 4; ++sub) {
                bf16x8 kb = *(const bf16x8*)&Ks[sub * 16 + lo][kk * 32 + hi * 8];
                s[sub] = __builtin_amdgcn_mfma_f32_16x16x32_bf16(qa[kk], kb, s[sub], 0, 0, 0);
            }
        }

        // tail key mask only
        if (m0 + 64 > N_KEY) {
#pragma unroll
            for (int sub = 0; sub < 4; ++sub) {
                int gm = m0 + sub * 16 + lo;
                if (gm >= N_KEY) {
#pragma unroll
                    for (int reg = 0; reg < 4; ++reg) s[sub][reg] = -1e30f;
                }
            }
        }

        // online softmax
        float corr[4];
#pragma unroll
        for (int reg = 0; reg < 4; ++reg) {
            float rm = fmaxf(fmaxf(s[0][reg], s[1][reg]), fmaxf(s[2][reg], s[3][reg]));
            rm = grp16_max(rm);
            float mnew = fmaxf(m_run[reg], rm);
            corr[reg] = __expf(m_run[reg] - mnew);
            float ps = 0.f;
#pragma unroll
            for (int sub = 0; sub < 4; ++sub) {
                float pp = __expf(s[sub][reg] - mnew);
                s[sub][reg] = pp; ps += pp;
            }
            ps = grp16_sum(ps);
            l_run[reg] = l_run[reg] * corr[reg] + ps;
            m_run[reg] = mnew;
        }
#pragma unroll
        for (int dsub = 0; dsub < 4; ++dsub)
#pragma unroll
            for (int reg = 0; reg < 4; ++reg) o[dsub][reg] *= corr[reg];

        // P -> LDS bf16 (wave-private rows)
#pragma unroll
        for (int sub = 0; sub < 4; ++sub)
#pragma unroll
            for (int reg = 0; reg < 4; ++reg)
                Ps[wave * 16 + hi * 4 + reg][sub * 16 + lo] = cvt_native(s[sub][reg]);

        // O += P @ V
#pragma unroll
        for (int kh2 = 0; kh2 < 2; ++kh2) {
            bf16x8 pa = *(const bf16x8*)&Ps[wave * 16 + lo][kh2 * 32 + hi * 8];
#pragma unroll
            for (int dsub = 0; dsub < 4; ++dsub) {
                bf16x8 vb = *(const bf16x8*)&Vt[dsub * 16 + lo][kh2 * 32 + hi * 8];
                o[dsub] = __builtin_amdgcn_mfma_f32_16x16x32_bf16(pa, vb, o[dsub], 0, 0, 0);
            }
        }
    }

    // epilogue
#pragma unroll
    for (int reg = 0; reg < 4; ++reg) {
        int rl = wave * 16 + hi * 4 + reg;
        int gq = q0 + rl;
        if (gq >= N_Q) continue;
        float inv = 1.f / l_run[reg];
#pragma unroll
        for (int dsub = 0; dsub < 4; ++dsub)
            aout[(size_t)gq * DIMM + head * HD + dsub * 16 + lo] = cvt_native(o[dsub][reg] * inv);
    }
}

// ---------------------------------------------------------------------------
extern "C" void kernel_launch(void* const* d_in, const int* in_sizes, int n_in,
                              void* d_out, int out_size, void* d_ws, size_t ws_size,
                              hipStream_t stream)
{
    const float* x      = (const float*)d_in[0];
    const float* qkv_w  = (const float*)d_in[1];
    const float* qkv_b  = (const float*)d_in[2];
    const float* proj_w = (const float*)d_in[3];
    const float* proj_b = (const float*)d_in[4];
    const float* pkw    = (const float*)d_in[5];
    const float* pvw    = (const float*)d_in[6];
    const float* nkg    = (const float*)d_in[7];
    const float* nkb    = (const float*)d_in[8];
    const float* nvg    = (const float*)d_in[9];
    const float* nvb    = (const float*)d_in[10];
    const float* rph    = (const float*)d_in[11];
    const float* rpw    = (const float*)d_in[12];
    const float* rpt    = (const float*)d_in[13];

    const size_t SZ_X     = (size_t)N_Q * DIMM;           // 4,817,664
    const size_t SZ_QKVW  = (size_t)3 * DIMM * DIMM;      // 1,769,472
    const size_t SZ_PROJW = (size_t)DIMM * DIMM;          //   589,824
    const size_t SZ_QHAT  = (size_t)NHEAD * N_Q * DQH;    // 9,635,328
    const size_t SZ_KV    = (size_t)NHEAD * N_Q * HD;     // 4,817,664
    const size_t SZ_KHAT  = (size_t)NHEAD * N_KEY * DQH;  // 2,409,984
    const size_t SZ_VPO   = (size_t)NHEAD * N_KEY * HD;   // 1,204,992

    ushort_t* xb     = (ushort_t*)d_ws;
    ushort_t* qkvwb  = xb + SZ_X;
    ushort_t* projwb = qkvwb + SZ_QKVW;
    ushort_t* qhat   = projwb + SZ_PROJW;
    ushort_t* kb     = qhat + SZ_QHAT;
    ushort_t* vb     = kb + SZ_KV;
    ushort_t* khat   = vb + SZ_KV;
    ushort_t* vpo    = khat + SZ_KHAT;
    ushort_t* aout   = vpo + SZ_VPO;
    float*    outp   = (float*)d_out;

    // 0) convert inputs to bf16
    cvt_bf16<<<2048, 256, 0, stream>>>(x, xb, (int)(SZ_X / 8));
    cvt_bf16<<<1024, 256, 0, stream>>>(qkv_w, qkvwb, (int)(SZ_QKVW / 8));
    cvt_bf16<<<512, 256, 0, stream>>>(proj_w, projwb, (int)(SZ_PROJW / 8));

    // 1) qkv GEMM (MFMA): q*SCALE -> qhat[:,0:64], k,v -> kb,vb
    gemm_mfma<1><<<dim3(36, 99), 256, 0, stream>>>(xb, qkvwb, qkv_b, N_Q, DIMM,
                                                   nullptr, qhat, kb, vb);
    // 2) pool + LN: K-hat (with one-hot rel channels) and V
    pool_ln<1><<<dim3((NHEAD * N_KEY + 3) / 4), 256, 0, stream>>>(kb, pkw, nkg, nkb, khat);
    pool_ln<0><<<dim3((NHEAD * N_KEY + 3) / 4), 256, 0, stream>>>(vb, pvw, nvg, nvb, vpo);
    // 3) rel-pos dots -> qhat cols 64..99; zero cls rel channels
    rel_dots<<<dim3((NHEAD * NSP) / 64), 256, 0, stream>>>(qhat, rph, rpw, rpt);
    cls_fix<<<dim3((NHEAD * 64 + 255) / 256), 256, 0, stream>>>(qhat);
    // 4) fused attention (MFMA, D=128)
    attn_mfma<<<dim3(99, NHEAD), 256, 0, stream>>>(qhat, khat, vpo, aout);
    // 5) proj GEMM (MFMA)
    gemm_mfma<0><<<dim3(12, 99), 256, 0, stream>>>(aout, projwb, proj_b, N_Q, DIMM,
                                                   outp, nullptr, nullptr, nullptr);
}

// Round 4
// 383.526 us; speedup vs baseline: 3.7934x; 1.0120x over previous
//
#include <hip/hip_runtime.h>

#define N_Q   6273
#define N_KEY 1569
#define NHEAD 12
#define HD    64
#define DQH   128     // augmented head dim
#define DIMM  768
#define NSP   6272
#define SCALE 0.125f
#define LOG2E 1.44269504f
#define QSC   (SCALE * LOG2E)
#define EPSLN 1e-5f
#define QBLK  128
#define DEFER_THR 11.5f   // 8 nats in log2 units

typedef __bf16 bf16x8 __attribute__((ext_vector_type(8)));
typedef float  f32x4  __attribute__((ext_vector_type(4)));
typedef unsigned short ushort_t;

__device__ __forceinline__ ushort_t f2bf(float f) {
    union { float f; unsigned u; } v; v.f = f;
    unsigned r = (v.u + 0x7FFFu + ((v.u >> 16) & 1u)) >> 16;
    return (ushort_t)r;
}
__device__ __forceinline__ float bf2f(ushort_t b) {
    union { unsigned u; float f; } v; v.u = ((unsigned)b) << 16;
    return v.f;
}
__device__ __forceinline__ float bflo(unsigned u) {
    union { unsigned a; float f; } v; v.a = u << 16; return v.f;
}
__device__ __forceinline__ float bfhi(unsigned u) {
    union { unsigned a; float f; } v; v.a = u & 0xffff0000u; return v.f;
}
__device__ __forceinline__ ushort_t cvt_native(float f) {
    __bf16 h = (__bf16)f;
    return *(ushort_t*)&h;
}
__device__ __forceinline__ float grp16_max(float v) {
#pragma unroll
    for (int off = 1; off < 16; off <<= 1) v = fmaxf(v, __shfl_xor(v, off, 16));
    return v;
}
__device__ __forceinline__ float grp16_sum(float v) {
#pragma unroll
    for (int off = 1; off < 16; off <<= 1) v += __shfl_xor(v, off, 16);
    return v;
}

// ---------------------------------------------------------------------------
// fp32 -> bf16 convert, 3 sources, contiguous destination. 8 elems/thread.
// ---------------------------------------------------------------------------
__global__ __launch_bounds__(256) void cvt3_bf16(
    const float* __restrict__ s0, const float* __restrict__ s1,
    const float* __restrict__ s2, ushort_t* __restrict__ dst,
    int n0, int n1, int n2)
{
    int total = n0 + n1 + n2;
    int stride = gridDim.x * 256;
    for (int i = blockIdx.x * 256 + threadIdx.x; i < total; i += stride) {
        const float* src; int j;
        if (i < n0)           { src = s0; j = i; }
        else if (i < n0 + n1) { src = s1; j = i - n0; }
        else                  { src = s2; j = i - n0 - n1; }
        const float4* s4 = (const float4*)src + (size_t)j * 2;
        float4 a = s4[0], b = s4[1];
        uint4 o;
        o.x = (unsigned)f2bf(a.x) | ((unsigned)f2bf(a.y) << 16);
        o.y = (unsigned)f2bf(a.z) | ((unsigned)f2bf(a.w) << 16);
        o.z = (unsigned)f2bf(b.x) | ((unsigned)f2bf(b.y) << 16);
        o.w = (unsigned)f2bf(b.z) | ((unsigned)f2bf(b.w) << 16);
        *(uint4*)&dst[(size_t)i * 8] = o;
    }
}

// ---------------------------------------------------------------------------
// bf16 MFMA GEMM: C = A[M,K] @ B[Ncols,K]^T + bias. 64x64 tile, BK=128.
// MODE 0: fp32 row-major store (width DIMM).
// MODE 1: qkv scatter; q -> qhat[head][N_Q][128] cols 0..63 scaled by QSC;
//         k,v -> [head][N_Q][64] bf16.
// ---------------------------------------------------------------------------
template <int MODE>
__global__ __launch_bounds__(256) void gemm_mfma(
    const ushort_t* __restrict__ A, const ushort_t* __restrict__ B,
    const float* __restrict__ bias, int M, int K,
    float* __restrict__ Cf, ushort_t* __restrict__ qd, ushort_t* __restrict__ kd,
    ushort_t* __restrict__ vd)
{
    __shared__ ushort_t As[64][136];
    __shared__ ushort_t Bs[64][136];
    const int tid = threadIdx.x;
    const int wave = tid >> 6, lane = tid & 63;
    const int lo = lane & 15, hi = lane >> 4;
    const int row0 = blockIdx.y * 64, col0 = blockIdx.x * 64;

    f32x4 acc[4];
#pragma unroll
    for (int s = 0; s < 4; ++s)
#pragma unroll
        for (int r = 0; r < 4; ++r) acc[s][r] = 0.f;

    for (int k0 = 0; k0 < K; k0 += 128) {
        __syncthreads();
#pragma unroll
        for (int i = 0; i < 4; ++i) {
            int c = tid + i * 256;
            int r = c >> 4, cg = c & 15;
            int gr = row0 + r;
            uint4 va = make_uint4(0, 0, 0, 0);
            if (gr < M) va = *(const uint4*)&A[(size_t)gr * K + k0 + cg * 8];
            *(uint4*)&As[r][cg * 8] = va;
            uint4 vb = *(const uint4*)&B[(size_t)(col0 + r) * K + k0 + cg * 8];
            *(uint4*)&Bs[r][cg * 8] = vb;
        }
        __syncthreads();
#pragma unroll
        for (int ks = 0; ks < 4; ++ks) {
            bf16x8 a = *(const bf16x8*)&As[wave * 16 + lo][ks * 32 + hi * 8];
#pragma unroll
            for (int sub = 0; sub < 4; ++sub) {
                bf16x8 b = *(const bf16x8*)&Bs[sub * 16 + lo][ks * 32 + hi * 8];
                acc[sub] = __builtin_amdgcn_mfma_f32_16x16x32_bf16(a, b, acc[sub], 0, 0, 0);
            }
        }
    }

#pragma unroll
    for (int sub = 0; sub < 4; ++sub) {
#pragma unroll
        for (int reg = 0; reg < 4; ++reg) {
            int r = row0 + wave * 16 + hi * 4 + reg;
            if (r >= M) continue;
            int ccol = col0 + sub * 16 + lo;
            float val = acc[sub][reg] + bias[ccol];
            if (MODE == 0) {
                Cf[(size_t)r * DIMM + ccol] = val;
            } else {
                int which = ccol / DIMM;
                int rem = ccol - which * DIMM;
                int head = rem >> 6, d = rem & 63;
                if (which == 0) {
                    qd[((size_t)head * N_Q + r) * DQH + d] = f2bf(val * QSC);
                } else {
                    ushort_t* dst = (which == 1) ? kd : vd;
                    dst[((size_t)head * N_Q + r) * HD + d] = f2bf(val);
                }
            }
        }
    }
}

// ---------------------------------------------------------------------------
// Depthwise 3x3x3 pool (stride 1,2,2, pad 1) + LayerNorm over HD, bf16.
// blockIdx.y == 0: K path -> K-hat rows [LN k | one-hot(kh,kw,kt) | zeros]
// blockIdx.y == 1: V path -> plain 64-wide rows.
// ---------------------------------------------------------------------------
__global__ __launch_bounds__(256) void pool_ln2(
    const ushort_t* __restrict__ kin, const ushort_t* __restrict__ vin,
    const float* __restrict__ wkk, const float* __restrict__ wkv,
    const float* __restrict__ gk, const float* __restrict__ bk,
    const float* __restrict__ gv, const float* __restrict__ bv,
    ushort_t* __restrict__ kout, ushort_t* __restrict__ vout)
{
    const int is_k = (blockIdx.y == 0);
    const ushort_t* in = is_k ? kin : vin;
    const float* wk = is_k ? wkk : wkv;
    const float* g  = is_k ? gk : gv;
    const float* b  = is_k ? bk : bv;

    __shared__ float ws_s[27][64];
    const int tid = threadIdx.x;
    for (int e = tid; e < 27 * 64; e += 256) {
        int d = e / 27, tap = e - d * 27;
        ws_s[tap][d] = wk[e];
    }
    __syncthreads();

    const int wave = tid >> 6, lane = tid & 63;
    const int pos = blockIdx.x * 4 + wave;
    if (pos >= NHEAD * N_KEY) return;
    const int head = pos / N_KEY;
    const int idx = pos - head * N_KEY;
    const ushort_t* base = in + (size_t)head * N_Q * HD;

    float val;
    if (idx == 0) {
        val = bf2f(base[lane]);
    } else {
        int p = idx - 1;
        int t1 = p / 196;
        int h1 = (p / 14) % 14;
        int w1 = p % 14;
        val = 0.f;
#pragma unroll
        for (int dt = 0; dt < 3; ++dt) {
            int t = t1 + dt - 1;
            if (t < 0 || t >= 8) continue;
#pragma unroll
            for (int dh = 0; dh < 3; ++dh) {
                int h = 2 * h1 + dh - 1;
                if (h < 0 || h >= 28) continue;
#pragma unroll
                for (int dw = 0; dw < 3; ++dw) {
                    int w = 2 * w1 + dw - 1;
                    if (w < 0 || w >= 28) continue;
                    int n = 1 + (t * 28 + h) * 28 + w;
                    val += bf2f(base[(size_t)n * HD + lane]) * ws_s[(dt * 3 + dh) * 3 + dw][lane];
                }
            }
        }
    }
    float mu = val;
#pragma unroll
    for (int off = 1; off < 64; off <<= 1) mu += __shfl_xor(mu, off, 64);
    mu *= (1.f / 64.f);
    float dv = val - mu;
    float var = dv * dv;
#pragma unroll
    for (int off = 1; off < 64; off <<= 1) var += __shfl_xor(var, off, 64);
    var *= (1.f / 64.f);
    float ln = dv * rsqrtf(var + EPSLN) * g[lane] + b[lane];

    if (!is_k) {
        vout[(size_t)pos * HD + lane] = f2bf(ln);
    } else {
        kout[(size_t)pos * DQH + lane] = f2bf(ln);
        float oh = 0.f;
        if (idx > 0) {
            int p = idx - 1;
            int kt = p / 196, kh = (p / 14) % 14, kw = p % 14;
            if ((lane < 14 && lane == kh) ||
                (lane >= 14 && lane < 28 && (lane - 14) == kw) ||
                (lane >= 28 && lane < 36 && (lane - 28) == kt))
                oh = 1.f;
        }
        kout[(size_t)pos * DQH + 64 + lane] = f2bf(oh);
    }
}

// ---------------------------------------------------------------------------
// Rel-pos dots -> Q-hat cols 64..99 (bf16, carries LOG2E via q-scale x8).
// Last block zeroes cls rel channels.
// ---------------------------------------------------------------------------
__global__ __launch_bounds__(256) void rel_dots(
    ushort_t* __restrict__ qhat, const float* __restrict__ rh,
    const float* __restrict__ rw, const float* __restrict__ rt)
{
    const int tid = threadIdx.x;
    if (blockIdx.x == (NHEAD * NSP) / 64) {
        // cls fix: zero rel channels of each head's q row 0
        for (int e = tid; e < NHEAD * 64; e += 256) {
            int head = e >> 6, c = e & 63;
            qhat[((size_t)head * N_Q) * DQH + 64 + c] = 0;
        }
        return;
    }

    __shared__ float Rs[125][65];   // rows 0..54 Rh, 55..109 Rw, 110..124 Rt
    for (int e = tid; e < 125 * 64; e += 256) {
        int r = e >> 6, c = e & 63;
        float v = (r < 55) ? rh[r * 64 + c]
                : (r < 110) ? rw[(r - 55) * 64 + c]
                            : rt[(r - 110) * 64 + c];
        Rs[r][c] = v;
    }
    __syncthreads();

    const int wave = tid >> 6, lane = tid & 63;
#pragma unroll 1
    for (int it = 0; it < 16; ++it) {
        int row = blockIdx.x * 64 + wave * 16 + it;   // in [0, NHEAD*NSP)
        int head = row / NSP;
        int qs = row - head * NSP;
        ushort_t* qrow = qhat + ((size_t)head * N_Q + 1 + qs) * DQH;
        int t = qs / 784, h = (qs / 28) % 28, w = qs % 28;
        int ridx;
        if (lane < 14)      ridx = h - 2 * lane + 26;
        else if (lane < 28) ridx = 55 + (w - 2 * (lane - 14) + 26);
        else if (lane < 36) ridx = 110 + (t - (lane - 28) + 7);
        else                ridx = 0;

        float s = 0.f;
#pragma unroll
        for (int cq = 0; cq < 8; ++cq) {
            uint2 qv = *(const uint2*)&qrow[cq * 8];       // broadcast read
            uint2 qv2 = *(const uint2*)&qrow[cq * 8 + 4];
            const float* Rp = &Rs[ridx][cq * 8];
            s += bflo(qv.x) * Rp[0] + bfhi(qv.x) * Rp[1]
               + bflo(qv.y) * Rp[2] + bfhi(qv.y) * Rp[3]
               + bflo(qv2.x) * Rp[4] + bfhi(qv2.x) * Rp[5]
               + bflo(qv2.y) * Rp[6] + bfhi(qv2.y) * Rp[7];
        }
        // q-hat cols carry QSC = SCALE*LOG2E; rel channel needs LOG2E*(q.R)
        // = (dot with q*SCALE*LOG2E) * 8
        if (lane < 36) qrow[64 + lane] = f2bf(s * 8.0f);
    }
}

// ---------------------------------------------------------------------------
// Fused flash attention, D=128 augmented, exp2 domain, defer-max rescale.
// Block = (128 q, head), 8 waves x 16 q rows. out: bf16 [N_Q][DIMM]
// ---------------------------------------------------------------------------
__global__ __launch_bounds__(512, 4) void attn_mfma(
    const ushort_t* __restrict__ qhat, const ushort_t* __restrict__ khat,
    const ushort_t* __restrict__ vp, ushort_t* __restrict__ aout)
{
    __shared__ ushort_t Ks[64][136];
    __shared__ ushort_t Vt[64][72];
    __shared__ ushort_t Ps[128][72];

    const int tid = threadIdx.x;
    const int wave = tid >> 6, lane = tid & 63;
    const int lo = lane & 15, hi = lane >> 4;
    const int head = blockIdx.y;
    const int q0 = blockIdx.x * QBLK;

    // Q-hat fragments (D=128 -> 4 frags), wave owns rows q0+wave*16..+15
    bf16x8 qa[4];
    {
        int qrow = q0 + wave * 16 + lo;
        if (qrow < N_Q) {
            const ushort_t* qpt = &qhat[((size_t)head * N_Q + qrow) * DQH];
#pragma unroll
            for (int j = 0; j < 4; ++j) qa[j] = *(const bf16x8*)&qpt[j * 32 + hi * 8];
        } else {
#pragma unroll
            for (int j = 0; j < 4; ++j)
#pragma unroll
                for (int e = 0; e < 8; ++e) qa[j][e] = (__bf16)0.0f;
        }
    }

    float m_run[4], l_run[4];
    f32x4 o[4];
#pragma unroll
    for (int i = 0; i < 4; ++i) {
        m_run[i] = -1e30f; l_run[i] = 0.f;
#pragma unroll
        for (int r = 0; r < 4; ++r) o[i][r] = 0.f;
    }

    for (int m0 = 0; m0 < N_KEY; m0 += 64) {
        __syncthreads();
        // stage K-hat (64 keys x 128 cols): 2 x 512 threads x 8 elems
#pragma unroll
        for (int i = 0; i < 2; ++i) {
            int c = tid + i * 512;
            int kr = c >> 4, cg = c & 15;
            int gm = m0 + kr;
            uint4 kv = make_uint4(0, 0, 0, 0);
            if (gm < N_KEY) kv = *(const uint4*)&khat[((size_t)head * N_KEY + gm) * DQH + cg * 8];
            *(uint4*)&Ks[kr][cg * 8] = kv;
        }
        // stage V transposed: 512 threads x 8 elems
        {
            int key = tid & 63, d0 = (tid >> 6) * 8;
            int gm = m0 + key;
            uint4 vv = make_uint4(0, 0, 0, 0);
            if (gm < N_KEY) vv = *(const uint4*)&vp[((size_t)head * N_KEY + gm) * HD + d0];
            ushort_t tmp[8];
            *(uint4*)tmp = vv;
#pragma unroll
            for (int j = 0; j < 8; ++j) Vt[d0 + j][key] = tmp[j];
        }
        __syncthreads();

        // S = Q-hat @ K-hat^T (scale + rel-pos bias folded, log2 domain)
        f32x4 s[4];
#pragma unroll
        for (int sub = 0; sub < 4; ++sub)
#pragma unroll
            for (int r = 0; r < 4; ++r) s[sub][r] = 0.f;
#pragma unroll
        for (int kk = 0; kk < 4; ++kk) {
#pragma unroll
            for (int sub = 0; sub < 4; ++sub) {
                bf16x8 kb = *(const bf16x8*)&Ks[sub * 16 + lo][kk * 32 + hi * 8];
                s[sub] = __builtin_amdgcn_mfma_f32_16x16x32_bf16(qa[kk], kb, s[sub], 0, 0, 0);
            }
        }

        // tail key mask
        if (m0 + 64 > N_KEY) {
#pragma unroll
            for (int sub = 0; sub < 4; ++sub) {
                int gm = m0 + sub * 16 + lo;
                if (gm >= N_KEY) {
#pragma unroll
                    for (int reg = 0; reg < 4; ++reg) s[sub][reg] = -1e30f;
                }
            }
        }

        // online softmax with defer-max
        float rm[4];
        float need = -1e30f;
#pragma unroll
        for (int reg = 0; reg < 4; ++reg) {
            float x = fmaxf(fmaxf(s[0][reg], s[1][reg]), fmaxf(s[2][reg], s[3][reg]));
            x = grp16_max(x);
            rm[reg] = x;
            need = fmaxf(need, x - m_run[reg]);
        }
        if (__any(need > DEFER_THR)) {
            // full rescale path
#pragma unroll
            for (int reg = 0; reg < 4; ++reg) {
                float mnew = fmaxf(m_run[reg], rm[reg]);
                float corr = exp2f(m_run[reg] - mnew);
                float ps = 0.f;
#pragma unroll
                for (int sub = 0; sub < 4; ++sub) {
                    float pp = exp2f(s[sub][reg] - mnew);
                    s[sub][reg] = pp; ps += pp;
                }
                ps = grp16_sum(ps);
                l_run[reg] = l_run[reg] * corr + ps;
                m_run[reg] = mnew;
#pragma unroll
                for (int dsub = 0; dsub < 4; ++dsub) o[dsub][reg] *= corr;
            }
        } else {
            // deferred: keep old max, no O rescale
#pragma unroll
            for (int reg = 0; reg < 4; ++reg) {
                float ps = 0.f;
#pragma unroll
                for (int sub = 0; sub < 4; ++sub) {
                    float pp = exp2f(s[sub][reg] - m_run[reg]);
                    s[sub][reg] = pp; ps += pp;
                }
                ps = grp16_sum(ps);
                l_run[reg] += ps;
            }
        }

        // P -> LDS bf16 (wave-private rows)
#pragma unroll
        for (int sub = 0; sub < 4; ++sub)
#pragma unroll
            for (int reg = 0; reg < 4; ++reg)
                Ps[wave * 16 + hi * 4 + reg][sub * 16 + lo] = cvt_native(s[sub][reg]);

        // O += P @ V
#pragma unroll
        for (int kh2 = 0; kh2 < 2; ++kh2) {
            bf16x8 pa = *(const bf16x8*)&Ps[wave * 16 + lo][kh2 * 32 + hi * 8];
#pragma unroll
            for (int dsub = 0; dsub < 4; ++dsub) {
                bf16x8 vb = *(const bf16x8*)&Vt[dsub * 16 + lo][kh2 * 32 + hi * 8];
                o[dsub] = __builtin_amdgcn_mfma_f32_16x16x32_bf16(pa, vb, o[dsub], 0, 0, 0);
            }
        }
    }

    // epilogue
#pragma unroll
    for (int reg = 0; reg < 4; ++reg) {
        int rl = wave * 16 + hi * 4 + reg;
        int gq = q0 + rl;
        if (gq >= N_Q) continue;
        float inv = 1.f / l_run[reg];
#pragma unroll
        for (int dsub = 0; dsub < 4; ++dsub)
            aout[(size_t)gq * DIMM + head * HD + dsub * 16 + lo] = cvt_native(o[dsub][reg] * inv);
    }
}

// ---------------------------------------------------------------------------
extern "C" void kernel_launch(void* const* d_in, const int* in_sizes, int n_in,
                              void* d_out, int out_size, void* d_ws, size_t ws_size,
                              hipStream_t stream)
{
    const float* x      = (const float*)d_in[0];
    const float* qkv_w  = (const float*)d_in[1];
    const float* qkv_b  = (const float*)d_in[2];
    const float* proj_w = (const float*)d_in[3];
    const float* proj_b = (const float*)d_in[4];
    const float* pkw    = (const float*)d_in[5];
    const float* pvw    = (const float*)d_in[6];
    const float* nkg    = (const float*)d_in[7];
    const float* nkb    = (const float*)d_in[8];
    const float* nvg    = (const float*)d_in[9];
    const float* nvb    = (const float*)d_in[10];
    const float* rph    = (const float*)d_in[11];
    const float* rpw    = (const float*)d_in[12];
    const float* rpt    = (const float*)d_in[13];

    const size_t SZ_X     = (size_t)N_Q * DIMM;           // 4,817,664
    const size_t SZ_QKVW  = (size_t)3 * DIMM * DIMM;      // 1,769,472
    const size_t SZ_PROJW = (size_t)DIMM * DIMM;          //   589,824
    const size_t SZ_QHAT  = (size_t)NHEAD * N_Q * DQH;    // 9,635,328
    const size_t SZ_KV    = (size_t)NHEAD * N_Q * HD;     // 4,817,664
    const size_t SZ_KHAT  = (size_t)NHEAD * N_KEY * DQH;  // 2,409,984
    const size_t SZ_VPO   = (size_t)NHEAD * N_KEY * HD;   // 1,204,992

    ushort_t* xb     = (ushort_t*)d_ws;
    ushort_t* qkvwb  = xb + SZ_X;
    ushort_t* projwb = qkvwb + SZ_QKVW;
    ushort_t* qhat   = projwb + SZ_PROJW;
    ushort_t* kb     = qhat + SZ_QHAT;
    ushort_t* vb     = kb + SZ_KV;
    ushort_t* khat   = vb + SZ_KV;
    ushort_t* vpo    = khat + SZ_KHAT;
    ushort_t* aout   = vpo + SZ_VPO;
    float*    outp   = (float*)d_out;

    // 0) convert inputs to bf16 (xb, qkvwb, projwb are contiguous)
    cvt3_bf16<<<2048, 256, 0, stream>>>(x, qkv_w, proj_w, xb,
                                        (int)(SZ_X / 8), (int)(SZ_QKVW / 8),
                                        (int)(SZ_PROJW / 8));
    // 1) qkv GEMM (MFMA): q*QSC -> qhat[:,0:64], k,v -> kb,vb
    gemm_mfma<1><<<dim3(36, 99), 256, 0, stream>>>(xb, qkvwb, qkv_b, N_Q, DIMM,
                                                   nullptr, qhat, kb, vb);
    // 2) pool + LN (K-hat with one-hot rel channels; V plain)
    pool_ln2<<<dim3((NHEAD * N_KEY + 3) / 4, 2), 256, 0, stream>>>(
        kb, vb, pkw, pvw, nkg, nkb, nvg, nvb, khat, vpo);
    // 3) rel-pos dots -> qhat cols 64..99 (+ cls fix in last block)
    rel_dots<<<dim3((NHEAD * NSP) / 64 + 1), 256, 0, stream>>>(qhat, rph, rpw, rpt);
    // 4) fused attention (MFMA, D=128, 128-q blocks)
    attn_mfma<<<dim3((N_Q + QBLK - 1) / QBLK, NHEAD), 512, 0, stream>>>(
        qhat, khat, vpo, aout);
    // 5) proj GEMM (MFMA)
    gemm_mfma<0><<<dim3(12, 99), 256, 0, stream>>>(aout, projwb, proj_b, N_Q, DIMM,
                                                   outp, nullptr, nullptr, nullptr);
}

// Round 5
// 316.071 us; speedup vs baseline: 4.6030x; 1.2134x over previous
//
#include <hip/hip_runtime.h>

#define N_Q   6273
#define N_KEY 1569
#define NHEAD 12
#define HD    64
#define DQH   128     // augmented head dim
#define DIMM  768
#define NSP   6272
#define SCALE 0.125f
#define LOG2E 1.44269504f
#define QSC   (SCALE * LOG2E)
#define EPSLN 1e-5f
#define DEFER_THR 11.5f   // 8 nats in log2 units

typedef __bf16 bf16x8 __attribute__((ext_vector_type(8)));
typedef float  f32x4  __attribute__((ext_vector_type(4)));
typedef unsigned short ushort_t;
typedef unsigned int uint_t;

__device__ __forceinline__ ushort_t f2bf(float f) {
    union { float f; unsigned u; } v; v.f = f;
    unsigned r = (v.u + 0x7FFFu + ((v.u >> 16) & 1u)) >> 16;
    return (ushort_t)r;
}
__device__ __forceinline__ float bf2f(ushort_t b) {
    union { unsigned u; float f; } v; v.u = ((unsigned)b) << 16;
    return v.f;
}
__device__ __forceinline__ float bflo(unsigned u) {
    union { unsigned a; float f; } v; v.a = u << 16; return v.f;
}
__device__ __forceinline__ float bfhi(unsigned u) {
    union { unsigned a; float f; } v; v.a = u & 0xffff0000u; return v.f;
}
__device__ __forceinline__ ushort_t cvt_native(float f) {
    __bf16 h = (__bf16)f;
    return *(ushort_t*)&h;
}
__device__ __forceinline__ uint_t pk2(float a, float b) {
    return (uint_t)cvt_native(a) | ((uint_t)cvt_native(b) << 16);
}
__device__ __forceinline__ void gload_lds16(const ushort_t* g, ushort_t* l) {
    __builtin_amdgcn_global_load_lds(
        (const __attribute__((address_space(1))) void*)g,
        (__attribute__((address_space(3))) void*)l, 16, 0, 0);
}

// ---------------------------------------------------------------------------
// fp32 -> bf16 convert, 3 sources, contiguous destination. 8 elems/thread.
// ---------------------------------------------------------------------------
__global__ __launch_bounds__(256) void cvt3_bf16(
    const float* __restrict__ s0, const float* __restrict__ s1,
    const float* __restrict__ s2, ushort_t* __restrict__ dst,
    int n0, int n1, int n2)
{
    int total = n0 + n1 + n2;
    int stride = gridDim.x * 256;
    for (int i = blockIdx.x * 256 + threadIdx.x; i < total; i += stride) {
        const float* src; int j;
        if (i < n0)           { src = s0; j = i; }
        else if (i < n0 + n1) { src = s1; j = i - n0; }
        else                  { src = s2; j = i - n0 - n1; }
        const float4* s4 = (const float4*)src + (size_t)j * 2;
        float4 a = s4[0], b = s4[1];
        uint4 o;
        o.x = (unsigned)f2bf(a.x) | ((unsigned)f2bf(a.y) << 16);
        o.y = (unsigned)f2bf(a.z) | ((unsigned)f2bf(a.w) << 16);
        o.z = (unsigned)f2bf(b.x) | ((unsigned)f2bf(b.y) << 16);
        o.w = (unsigned)f2bf(b.z) | ((unsigned)f2bf(b.w) << 16);
        *(uint4*)&dst[(size_t)i * 8] = o;
    }
}

// ---------------------------------------------------------------------------
// bf16 MFMA GEMM, m97-structure: 128x128 tile, BK=64, global_load_lds w=16,
// pre-swizzled source + XOR-swizzled ds_read (st-16 pattern).
// C = A[M,K] @ B[Ncols,K]^T + bias.
// MODE 0: fp32 row-major store (width DIMM).
// MODE 1: qkv scatter; q -> qhat[head][N_Q][128] cols 0..63 scaled by QSC;
//         k,v -> [head][N_Q][64] bf16.
// ---------------------------------------------------------------------------
template <int MODE>
__global__ __launch_bounds__(256) void gemm_mfma(
    const ushort_t* __restrict__ A, const ushort_t* __restrict__ B,
    const float* __restrict__ bias, int M, int K,
    float* __restrict__ Cf, ushort_t* __restrict__ qd, ushort_t* __restrict__ kd,
    ushort_t* __restrict__ vd)
{
    __shared__ ushort_t sm[16384];   // As [128][64] | Bs [128][64], swizzled
    ushort_t* As = sm;
    ushort_t* Bs = sm + 8192;
    const int tid = threadIdx.x;
    const int wave = tid >> 6, lane = tid & 63;
    const int lo = lane & 15, hi = lane >> 4;
    const int row0 = blockIdx.y * 128, col0 = blockIdx.x * 128;
    const int wr = wave >> 1, wc = wave & 1;

    f32x4 acc[4][4];
#pragma unroll
    for (int i = 0; i < 4; ++i)
#pragma unroll
        for (int j = 0; j < 4; ++j)
#pragma unroll
            for (int r = 0; r < 4; ++r) acc[i][j][r] = 0.f;

    const int sr = lane >> 3;          // 0..7 (row within 8-row chunk)
    const int scb = (lane & 7) * 16;   // byte col within 128B row

    for (int k0 = 0; k0 < K; k0 += 64) {
        __syncthreads();
#pragma unroll
        for (int i = 0; i < 4; ++i) {
            int t = wave * 4 + i;             // chunk 0..15 (1KB each)
            int r = t * 8 + sr;               // tile row 0..127
            int cbs = scb ^ ((r & 7) << 4);   // pre-swizzled source col-byte
            int ga = row0 + r; if (ga > M - 1) ga = M - 1;
            gload_lds16(&A[(size_t)ga * K + k0 + (cbs >> 1)], &As[t * 512]);
            gload_lds16(&B[(size_t)(col0 + r) * K + k0 + (cbs >> 1)], &Bs[t * 512]);
        }
        __syncthreads();

#pragma unroll
        for (int ks = 0; ks < 2; ++ks) {
            bf16x8 af[4], bfr[4];
#pragma unroll
            for (int s = 0; s < 4; ++s) {
                int ra = wr * 64 + s * 16 + lo;
                int ca = (ks * 64 + hi * 16) ^ ((ra & 7) << 4);
                af[s] = *(const bf16x8*)&As[ra * 64 + (ca >> 1)];
                int rb = wc * 64 + s * 16 + lo;
                int cb2 = (ks * 64 + hi * 16) ^ ((rb & 7) << 4);
                bfr[s] = *(const bf16x8*)&Bs[rb * 64 + (cb2 >> 1)];
            }
#pragma unroll
            for (int i = 0; i < 4; ++i)
#pragma unroll
                for (int j = 0; j < 4; ++j)
                    acc[i][j] = __builtin_amdgcn_mfma_f32_16x16x32_bf16(
                        af[i], bfr[j], acc[i][j], 0, 0, 0);
        }
    }

#pragma unroll
    for (int i = 0; i < 4; ++i) {
#pragma unroll
        for (int reg = 0; reg < 4; ++reg) {
            int r = row0 + wr * 64 + i * 16 + hi * 4 + reg;
            if (r >= M) continue;
#pragma unroll
            for (int j = 0; j < 4; ++j) {
                int c = col0 + wc * 64 + j * 16 + lo;
                float val = acc[i][j][reg] + bias[c];
                if (MODE == 0) {
                    Cf[(size_t)r * DIMM + c] = val;
                } else {
                    int which = c / DIMM;
                    int rem = c - which * DIMM;
                    int head = rem >> 6, d = rem & 63;
                    if (which == 0) {
                        qd[((size_t)head * N_Q + r) * DQH + d] = f2bf(val * QSC);
                    } else {
                        ushort_t* dst = (which == 1) ? kd : vd;
                        dst[((size_t)head * N_Q + r) * HD + d] = f2bf(val);
                    }
                }
            }
        }
    }
}

// ---------------------------------------------------------------------------
// Depthwise 3x3x3 pool (stride 1,2,2, pad 1) + LayerNorm over HD, bf16.
// blockIdx.y == 0: K path -> K-hat rows [LN k | one-hot(kh,kw,kt) | zeros]
// blockIdx.y == 1: V path -> plain 64-wide rows.
// ---------------------------------------------------------------------------
__global__ __launch_bounds__(256) void pool_ln2(
    const ushort_t* __restrict__ kin, const ushort_t* __restrict__ vin,
    const float* __restrict__ wkk, const float* __restrict__ wkv,
    const float* __restrict__ gk, const float* __restrict__ bk,
    const float* __restrict__ gv, const float* __restrict__ bv,
    ushort_t* __restrict__ kout, ushort_t* __restrict__ vout)
{
    const int is_k = (blockIdx.y == 0);
    const ushort_t* in = is_k ? kin : vin;
    const float* wk = is_k ? wkk : wkv;
    const float* g  = is_k ? gk : gv;
    const float* b  = is_k ? bk : bv;

    __shared__ float ws_s[27][64];
    const int tid = threadIdx.x;
    for (int e = tid; e < 27 * 64; e += 256) {
        int d = e / 27, tap = e - d * 27;
        ws_s[tap][d] = wk[e];
    }
    __syncthreads();

    const int wave = tid >> 6, lane = tid & 63;
    const int pos = blockIdx.x * 4 + wave;
    if (pos >= NHEAD * N_KEY) return;
    const int head = pos / N_KEY;
    const int idx = pos - head * N_KEY;
    const ushort_t* base = in + (size_t)head * N_Q * HD;

    float val;
    if (idx == 0) {
        val = bf2f(base[lane]);
    } else {
        int p = idx - 1;
        int t1 = p / 196;
        int h1 = (p / 14) % 14;
        int w1 = p % 14;
        val = 0.f;
#pragma unroll
        for (int dt = 0; dt < 3; ++dt) {
            int t = t1 + dt - 1;
            if (t < 0 || t >= 8) continue;
#pragma unroll
            for (int dh = 0; dh < 3; ++dh) {
                int h = 2 * h1 + dh - 1;
                if (h < 0 || h >= 28) continue;
#pragma unroll
                for (int dw = 0; dw < 3; ++dw) {
                    int w = 2 * w1 + dw - 1;
                    if (w < 0 || w >= 28) continue;
                    int n = 1 + (t * 28 + h) * 28 + w;
                    val += bf2f(base[(size_t)n * HD + lane]) * ws_s[(dt * 3 + dh) * 3 + dw][lane];
                }
            }
        }
    }
    float mu = val;
#pragma unroll
    for (int off = 1; off < 64; off <<= 1) mu += __shfl_xor(mu, off, 64);
    mu *= (1.f / 64.f);
    float dv = val - mu;
    float var = dv * dv;
#pragma unroll
    for (int off = 1; off < 64; off <<= 1) var += __shfl_xor(var, off, 64);
    var *= (1.f / 64.f);
    float ln = dv * rsqrtf(var + EPSLN) * g[lane] + b[lane];

    if (!is_k) {
        vout[(size_t)pos * HD + lane] = f2bf(ln);
    } else {
        kout[(size_t)pos * DQH + lane] = f2bf(ln);
        float oh = 0.f;
        if (idx > 0) {
            int p = idx - 1;
            int kt = p / 196, kh = (p / 14) % 14, kw = p % 14;
            if ((lane < 14 && lane == kh) ||
                (lane >= 14 && lane < 28 && (lane - 14) == kw) ||
                (lane >= 28 && lane < 36 && (lane - 28) == kt))
                oh = 1.f;
        }
        kout[(size_t)pos * DQH + 64 + lane] = f2bf(oh);
    }
}

// ---------------------------------------------------------------------------
// Rel-pos dots -> Q-hat cols 64..99 (bf16, carries LOG2E via q-scale x8).
// Last block zeroes cls rel channels.
// ---------------------------------------------------------------------------
__global__ __launch_bounds__(256) void rel_dots(
    ushort_t* __restrict__ qhat, const float* __restrict__ rh,
    const float* __restrict__ rw, const float* __restrict__ rt)
{
    const int tid = threadIdx.x;
    if (blockIdx.x == (NHEAD * NSP) / 64) {
        for (int e = tid; e < NHEAD * 64; e += 256) {
            int head = e >> 6, c = e & 63;
            qhat[((size_t)head * N_Q) * DQH + 64 + c] = 0;
        }
        return;
    }

    __shared__ float Rs[125][65];
    for (int e = tid; e < 125 * 64; e += 256) {
        int r = e >> 6, c = e & 63;
        float v = (r < 55) ? rh[r * 64 + c]
                : (r < 110) ? rw[(r - 55) * 64 + c]
                            : rt[(r - 110) * 64 + c];
        Rs[r][c] = v;
    }
    __syncthreads();

    const int wave = tid >> 6, lane = tid & 63;
#pragma unroll 1
    for (int it = 0; it < 16; ++it) {
        int row = blockIdx.x * 64 + wave * 16 + it;
        int head = row / NSP;
        int qs = row - head * NSP;
        ushort_t* qrow = qhat + ((size_t)head * N_Q + 1 + qs) * DQH;
        int t = qs / 784, h = (qs / 28) % 28, w = qs % 28;
        int ridx;
        if (lane < 14)      ridx = h - 2 * lane + 26;
        else if (lane < 28) ridx = 55 + (w - 2 * (lane - 14) + 26);
        else if (lane < 36) ridx = 110 + (t - (lane - 28) + 7);
        else                ridx = 0;

        float s = 0.f;
#pragma unroll
        for (int cq = 0; cq < 8; ++cq) {
            uint2 qv = *(const uint2*)&qrow[cq * 8];
            uint2 qv2 = *(const uint2*)&qrow[cq * 8 + 4];
            const float* Rp = &Rs[ridx][cq * 8];
            s += bflo(qv.x) * Rp[0] + bfhi(qv.x) * Rp[1]
               + bflo(qv.y) * Rp[2] + bfhi(qv.y) * Rp[3]
               + bflo(qv2.x) * Rp[4] + bfhi(qv2.x) * Rp[5]
               + bflo(qv2.y) * Rp[6] + bfhi(qv2.y) * Rp[7];
        }
        if (lane < 36) qrow[64 + lane] = f2bf(s * 8.0f);
    }
}

// ---------------------------------------------------------------------------
// Fused flash attention, swapped-operand form (lane owns one query).
// Block = (64 q, head), 4 waves x 16 q. Ks/Vt XOR-swizzled; P in-register;
// O^T accumulated, transposed via wave-private LDS bounce at the end.
// ---------------------------------------------------------------------------
__global__ __launch_bounds__(256) void attn_mfma(
    const ushort_t* __restrict__ qhat, const ushort_t* __restrict__ khat,
    const ushort_t* __restrict__ vp, ushort_t* __restrict__ aout)
{
    __shared__ ushort_t Ks[64 * 128];      // [key][128], swizzled
    __shared__ ushort_t Vt[64 * 64];       // [d][key],   swizzled
    __shared__ ushort_t Ob[4][16][88];     // per-wave O bounce

    const int tid = threadIdx.x;
    const int wave = tid >> 6, lane = tid & 63;
    const int lo = lane & 15, hi = lane >> 4;
    const int head = blockIdx.y;
    const int q0 = blockIdx.x * 64;
    const int qrow = q0 + wave * 16 + lo;   // this lane's query

    // Q-hat fragments (B-operand: col=q=lo, k-elems d = hi*8+j per 32-chunk)
    bf16x8 qa[4];
    if (qrow < N_Q) {
        const ushort_t* qpt = &qhat[((size_t)head * N_Q + qrow) * DQH];
#pragma unroll
        for (int j = 0; j < 4; ++j) qa[j] = *(const bf16x8*)&qpt[j * 32 + hi * 8];
    } else {
#pragma unroll
        for (int j = 0; j < 4; ++j)
#pragma unroll
            for (int e = 0; e < 8; ++e) qa[j][e] = (__bf16)0.0f;
    }

    float m_run = -1e30f, l_run = 0.f;
    f32x4 o[4];
#pragma unroll
    for (int i = 0; i < 4; ++i)
#pragma unroll
        for (int r = 0; r < 4; ++r) o[i][r] = 0.f;

    const bool oddh = (hi & 1) != 0;
    const bool toph = (hi >> 1) != 0;

    for (int m0 = 0; m0 < N_KEY; m0 += 64) {
        __syncthreads();
        // stage K-hat via global_load_lds, pre-swizzled source
#pragma unroll
        for (int i = 0; i < 4; ++i) {
            int t = wave * 4 + i;               // 1KB chunk 0..15
            int kr = t * 4 + hi;                // key row 0..63
            int cb = (lo * 16) ^ ((kr & 7) << 4);
            int gm = m0 + kr; if (gm > N_KEY - 1) gm = N_KEY - 1;
            gload_lds16(&khat[((size_t)head * N_KEY + gm) * DQH + (cb >> 1)],
                        &Ks[t * 512]);
        }
        // stage V transposed, swizzled scalar writes
#pragma unroll
        for (int i = 0; i < 2; ++i) {
            int c = tid + i * 256;
            int key = c & 63, d0 = (c >> 6) * 8;
            int gm = m0 + key; if (gm > N_KEY - 1) gm = N_KEY - 1;
            uint4 vv = *(const uint4*)&vp[((size_t)head * N_KEY + gm) * HD + d0];
            ushort_t tmp[8];
            *(uint4*)tmp = vv;
#pragma unroll
            for (int j = 0; j < 8; ++j)
                Vt[(d0 + j) * 64 + (key ^ (j * 8))] = tmp[j];
        }
        __syncthreads();

        // S^T = K-hat @ Q-hat^T : s[sub][reg] = S[key=sub*16+hi*4+reg][q=lo]
        f32x4 s[4];
#pragma unroll
        for (int sub = 0; sub < 4; ++sub)
#pragma unroll
            for (int r = 0; r < 4; ++r) s[sub][r] = 0.f;
#pragma unroll
        for (int kk = 0; kk < 4; ++kk) {
#pragma unroll
            for (int sub = 0; sub < 4; ++sub) {
                int rk = sub * 16 + lo;
                bf16x8 kf = *(const bf16x8*)&Ks[rk * 128 +
                            ((kk * 32 + hi * 8) ^ ((lo & 7) * 8))];
                s[sub] = __builtin_amdgcn_mfma_f32_16x16x32_bf16(kf, qa[kk], s[sub], 0, 0, 0);
            }
        }

        // tail key mask
        if (m0 + 64 > N_KEY) {
#pragma unroll
            for (int sub = 0; sub < 4; ++sub)
#pragma unroll
                for (int reg = 0; reg < 4; ++reg)
                    if (m0 + sub * 16 + hi * 4 + reg >= N_KEY) s[sub][reg] = -1e30f;
        }

        // scalar online softmax (lane owns one query row)
        float rm = s[0][0];
#pragma unroll
        for (int sub = 0; sub < 4; ++sub)
#pragma unroll
            for (int reg = 0; reg < 4; ++reg) rm = fmaxf(rm, s[sub][reg]);
        rm = fmaxf(rm, __shfl_xor(rm, 16));
        rm = fmaxf(rm, __shfl_xor(rm, 32));

        if (__any(rm - m_run > DEFER_THR)) {
            float mnew = fmaxf(m_run, rm);
            float corr = exp2f(m_run - mnew);
            float ps = 0.f;
#pragma unroll
            for (int sub = 0; sub < 4; ++sub)
#pragma unroll
                for (int reg = 0; reg < 4; ++reg) {
                    float pp = exp2f(s[sub][reg] - mnew);
                    s[sub][reg] = pp; ps += pp;
                }
            ps += __shfl_xor(ps, 16);
            ps += __shfl_xor(ps, 32);
            l_run = l_run * corr + ps;
            m_run = mnew;
#pragma unroll
            for (int i = 0; i < 4; ++i)
#pragma unroll
                for (int r = 0; r < 4; ++r) o[i][r] *= corr;
        } else {
            float ps = 0.f;
#pragma unroll
            for (int sub = 0; sub < 4; ++sub)
#pragma unroll
                for (int reg = 0; reg < 4; ++reg) {
                    float pp = exp2f(s[sub][reg] - m_run);
                    s[sub][reg] = pp; ps += pp;
                }
            ps += __shfl_xor(ps, 16);
            ps += __shfl_xor(ps, 32);
            l_run += ps;
        }

        // P^T pack + butterfly exchange -> PV B-frags; O^T += V^T @ P^T
#pragma unroll
        for (int kh2 = 0; kh2 < 2; ++kh2) {
            uint_t x0a = pk2(s[2 * kh2][0], s[2 * kh2][1]);
            uint_t x0b = pk2(s[2 * kh2][2], s[2 * kh2][3]);
            uint_t x1a = pk2(s[2 * kh2 + 1][0], s[2 * kh2 + 1][1]);
            uint_t x1b = pk2(s[2 * kh2 + 1][2], s[2 * kh2 + 1][3]);
            uint_t y0a = __shfl_xor(x0a, 16), y0b = __shfl_xor(x0b, 16);
            uint_t y1a = __shfl_xor(x1a, 16), y1b = __shfl_xor(x1b, 16);
            uint_t c0[4] = { oddh ? y0a : x0a, oddh ? y0b : x0b,
                             oddh ? x0a : y0a, oddh ? x0b : y0b };
            uint_t c1[4] = { oddh ? y1a : x1a, oddh ? y1b : x1b,
                             oddh ? x1a : y1a, oddh ? x1b : y1b };
            union { uint_t u[4]; bf16x8 v; } pw;
#pragma unroll
            for (int i2 = 0; i2 < 4; ++i2) {
                uint_t f0 = __shfl_xor(c0[i2], 32);
                uint_t f1 = __shfl_xor(c1[i2], 32);
                pw.u[i2] = toph ? (oddh ? c1[i2] : f1) : (oddh ? f0 : c0[i2]);
            }
#pragma unroll
            for (int sub_d = 0; sub_d < 4; ++sub_d) {
                bf16x8 vf = *(const bf16x8*)&Vt[(sub_d * 16 + lo) * 64 +
                            ((kh2 * 32 + hi * 8) ^ ((lo & 7) * 8))];
                o[sub_d] = __builtin_amdgcn_mfma_f32_16x16x32_bf16(vf, pw.v, o[sub_d], 0, 0, 0);
            }
        }
    }

    // epilogue: normalize, transpose via wave-private LDS bounce, store
    __syncthreads();
    float inv = 1.f / l_run;
#pragma unroll
    for (int sub_d = 0; sub_d < 4; ++sub_d)
#pragma unroll
        for (int reg = 0; reg < 4; ++reg)
            Ob[wave][lo][sub_d * 16 + hi * 4 + reg] = cvt_native(o[sub_d][reg] * inv);
    __syncthreads();
#pragma unroll
    for (int i = 0; i < 2; ++i) {
        int e = lane + i * 64;
        int r = e >> 3, cc = e & 7;
        int gq = q0 + wave * 16 + r;
        if (gq < N_Q) {
            uint4 ov = *(const uint4*)&Ob[wave][r][cc * 8];
            *(uint4*)&aout[(size_t)gq * DIMM + head * HD + cc * 8] = ov;
        }
    }
}

// ---------------------------------------------------------------------------
extern "C" void kernel_launch(void* const* d_in, const int* in_sizes, int n_in,
                              void* d_out, int out_size, void* d_ws, size_t ws_size,
                              hipStream_t stream)
{
    const float* x      = (const float*)d_in[0];
    const float* qkv_w  = (const float*)d_in[1];
    const float* qkv_b  = (const float*)d_in[2];
    const float* proj_w = (const float*)d_in[3];
    const float* proj_b = (const float*)d_in[4];
    const float* pkw    = (const float*)d_in[5];
    const float* pvw    = (const float*)d_in[6];
    const float* nkg    = (const float*)d_in[7];
    const float* nkb    = (const float*)d_in[8];
    const float* nvg    = (const float*)d_in[9];
    const float* nvb    = (const float*)d_in[10];
    const float* rph    = (const float*)d_in[11];
    const float* rpw    = (const float*)d_in[12];
    const float* rpt    = (const float*)d_in[13];

    const size_t SZ_X     = (size_t)N_Q * DIMM;
    const size_t SZ_QKVW  = (size_t)3 * DIMM * DIMM;
    const size_t SZ_PROJW = (size_t)DIMM * DIMM;
    const size_t SZ_QHAT  = (size_t)NHEAD * N_Q * DQH;
    const size_t SZ_KV    = (size_t)NHEAD * N_Q * HD;
    const size_t SZ_KHAT  = (size_t)NHEAD * N_KEY * DQH;
    const size_t SZ_VPO   = (size_t)NHEAD * N_KEY * HD;

    ushort_t* xb     = (ushort_t*)d_ws;
    ushort_t* qkvwb  = xb + SZ_X;
    ushort_t* projwb = qkvwb + SZ_QKVW;
    ushort_t* qhat   = projwb + SZ_PROJW;
    ushort_t* kb     = qhat + SZ_QHAT;
    ushort_t* vb     = kb + SZ_KV;
    ushort_t* khat   = vb + SZ_KV;
    ushort_t* vpo    = khat + SZ_KHAT;
    ushort_t* aout   = vpo + SZ_VPO;
    float*    outp   = (float*)d_out;

    // 0) convert inputs to bf16
    cvt3_bf16<<<2048, 256, 0, stream>>>(x, qkv_w, proj_w, xb,
                                        (int)(SZ_X / 8), (int)(SZ_QKVW / 8),
                                        (int)(SZ_PROJW / 8));
    // 1) qkv GEMM (128^2 tile, gload_lds): q*QSC -> qhat[:,0:64], k,v -> kb,vb
    gemm_mfma<1><<<dim3(18, 50), 256, 0, stream>>>(xb, qkvwb, qkv_b, N_Q, DIMM,
                                                   nullptr, qhat, kb, vb);
    // 2) pool + LN (K-hat with one-hot rel channels; V plain)
    pool_ln2<<<dim3((NHEAD * N_KEY + 3) / 4, 2), 256, 0, stream>>>(
        kb, vb, pkw, pvw, nkg, nkb, nvg, nvb, khat, vpo);
    // 3) rel-pos dots -> qhat cols 64..99 (+ cls fix in last block)
    rel_dots<<<dim3((NHEAD * NSP) / 64 + 1), 256, 0, stream>>>(qhat, rph, rpw, rpt);
    // 4) fused attention (swapped-operand, swizzled LDS)
    attn_mfma<<<dim3(99, NHEAD), 256, 0, stream>>>(qhat, khat, vpo, aout);
    // 5) proj GEMM
    gemm_mfma<0><<<dim3(6, 50), 256, 0, stream>>>(aout, projwb, proj_b, N_Q, DIMM,
                                                  outp, nullptr, nullptr, nullptr);
}

// Round 6
// 295.968 us; speedup vs baseline: 4.9157x; 1.0679x over previous
//
#include <hip/hip_runtime.h>

#define N_Q   6273
#define N_KEY 1569
#define NHEAD 12
#define HD    64
#define DQH   128     // augmented head dim
#define DIMM  768
#define NSP   6272
#define SCALE 0.125f
#define LOG2E 1.44269504f
#define QSC   (SCALE * LOG2E)
#define EPSLN 1e-5f
#define DEFER_THR 11.5f   // 8 nats in log2 units

typedef __bf16 bf16x8 __attribute__((ext_vector_type(8)));
typedef float  f32x4  __attribute__((ext_vector_type(4)));
typedef unsigned short ushort_t;
typedef unsigned int uint_t;

__device__ __forceinline__ ushort_t f2bf(float f) {
    union { float f; unsigned u; } v; v.f = f;
    unsigned r = (v.u + 0x7FFFu + ((v.u >> 16) & 1u)) >> 16;
    return (ushort_t)r;
}
__device__ __forceinline__ float bf2f(ushort_t b) {
    union { unsigned u; float f; } v; v.u = ((unsigned)b) << 16;
    return v.f;
}
__device__ __forceinline__ float bflo(unsigned u) {
    union { unsigned a; float f; } v; v.a = u << 16; return v.f;
}
__device__ __forceinline__ float bfhi(unsigned u) {
    union { unsigned a; float f; } v; v.a = u & 0xffff0000u; return v.f;
}
__device__ __forceinline__ ushort_t cvt_native(float f) {
    __bf16 h = (__bf16)f;
    return *(ushort_t*)&h;
}
__device__ __forceinline__ uint_t pk2(float a, float b) {
    return (uint_t)cvt_native(a) | ((uint_t)cvt_native(b) << 16);
}
__device__ __forceinline__ void gload_lds16(const ushort_t* g, ushort_t* l) {
    __builtin_amdgcn_global_load_lds(
        (const __attribute__((address_space(1))) void*)g,
        (__attribute__((address_space(3))) void*)l, 16, 0, 0);
}

// ---------------------------------------------------------------------------
// fp32 -> bf16 convert, 3 sources, contiguous destination. 8 elems/thread.
// ---------------------------------------------------------------------------
__global__ __launch_bounds__(256) void cvt3_bf16(
    const float* __restrict__ s0, const float* __restrict__ s1,
    const float* __restrict__ s2, ushort_t* __restrict__ dst,
    int n0, int n1, int n2)
{
    int total = n0 + n1 + n2;
    int stride = gridDim.x * 256;
    for (int i = blockIdx.x * 256 + threadIdx.x; i < total; i += stride) {
        const float* src; int j;
        if (i < n0)           { src = s0; j = i; }
        else if (i < n0 + n1) { src = s1; j = i - n0; }
        else                  { src = s2; j = i - n0 - n1; }
        const float4* s4 = (const float4*)src + (size_t)j * 2;
        float4 a = s4[0], b = s4[1];
        uint4 o;
        o.x = (unsigned)f2bf(a.x) | ((unsigned)f2bf(a.y) << 16);
        o.y = (unsigned)f2bf(a.z) | ((unsigned)f2bf(a.w) << 16);
        o.z = (unsigned)f2bf(b.x) | ((unsigned)f2bf(b.y) << 16);
        o.w = (unsigned)f2bf(b.z) | ((unsigned)f2bf(b.w) << 16);
        *(uint4*)&dst[(size_t)i * 8] = o;
    }
}

// ---------------------------------------------------------------------------
// bf16 MFMA GEMM, m97-structure: 128x128 tile, BK=64, global_load_lds w=16,
// pre-swizzled source + XOR-swizzled ds_read.
// MODE 0: fp32 row-major store. MODE 1: qkv scatter (q scaled by QSC).
// ---------------------------------------------------------------------------
template <int MODE>
__global__ __launch_bounds__(256) void gemm_mfma(
    const ushort_t* __restrict__ A, const ushort_t* __restrict__ B,
    const float* __restrict__ bias, int M, int K,
    float* __restrict__ Cf, ushort_t* __restrict__ qd, ushort_t* __restrict__ kd,
    ushort_t* __restrict__ vd)
{
    __shared__ ushort_t sm[16384];   // As [128][64] | Bs [128][64], swizzled
    ushort_t* As = sm;
    ushort_t* Bs = sm + 8192;
    const int tid = threadIdx.x;
    const int wave = tid >> 6, lane = tid & 63;
    const int lo = lane & 15, hi = lane >> 4;
    const int row0 = blockIdx.y * 128, col0 = blockIdx.x * 128;
    const int wr = wave >> 1, wc = wave & 1;

    f32x4 acc[4][4];
#pragma unroll
    for (int i = 0; i < 4; ++i)
#pragma unroll
        for (int j = 0; j < 4; ++j)
#pragma unroll
            for (int r = 0; r < 4; ++r) acc[i][j][r] = 0.f;

    const int sr = lane >> 3;
    const int scb = (lane & 7) * 16;

    for (int k0 = 0; k0 < K; k0 += 64) {
        __syncthreads();
#pragma unroll
        for (int i = 0; i < 4; ++i) {
            int t = wave * 4 + i;
            int r = t * 8 + sr;
            int cbs = scb ^ ((r & 7) << 4);
            int ga = row0 + r; if (ga > M - 1) ga = M - 1;
            gload_lds16(&A[(size_t)ga * K + k0 + (cbs >> 1)], &As[t * 512]);
            gload_lds16(&B[(size_t)(col0 + r) * K + k0 + (cbs >> 1)], &Bs[t * 512]);
        }
        __syncthreads();

#pragma unroll
        for (int ks = 0; ks < 2; ++ks) {
            bf16x8 af[4], bfr[4];
#pragma unroll
            for (int s = 0; s < 4; ++s) {
                int ra = wr * 64 + s * 16 + lo;
                int ca = (ks * 64 + hi * 16) ^ ((ra & 7) << 4);
                af[s] = *(const bf16x8*)&As[ra * 64 + (ca >> 1)];
                int rb = wc * 64 + s * 16 + lo;
                int cb2 = (ks * 64 + hi * 16) ^ ((rb & 7) << 4);
                bfr[s] = *(const bf16x8*)&Bs[rb * 64 + (cb2 >> 1)];
            }
#pragma unroll
            for (int i = 0; i < 4; ++i)
#pragma unroll
                for (int j = 0; j < 4; ++j)
                    acc[i][j] = __builtin_amdgcn_mfma_f32_16x16x32_bf16(
                        af[i], bfr[j], acc[i][j], 0, 0, 0);
        }
    }

#pragma unroll
    for (int i = 0; i < 4; ++i) {
#pragma unroll
        for (int reg = 0; reg < 4; ++reg) {
            int r = row0 + wr * 64 + i * 16 + hi * 4 + reg;
            if (r >= M) continue;
#pragma unroll
            for (int j = 0; j < 4; ++j) {
                int c = col0 + wc * 64 + j * 16 + lo;
                float val = acc[i][j][reg] + bias[c];
                if (MODE == 0) {
                    Cf[(size_t)r * DIMM + c] = val;
                } else {
                    int which = c / DIMM;
                    int rem = c - which * DIMM;
                    int head = rem >> 6, d = rem & 63;
                    if (which == 0) {
                        qd[((size_t)head * N_Q + r) * DQH + d] = f2bf(val * QSC);
                    } else {
                        ushort_t* dst = (which == 1) ? kd : vd;
                        dst[((size_t)head * N_Q + r) * HD + d] = f2bf(val);
                    }
                }
            }
        }
    }
}

// ---------------------------------------------------------------------------
// Depthwise 3x3x3 pool (stride 1,2,2, pad 1) + LayerNorm over HD, bf16.
// ---------------------------------------------------------------------------
__global__ __launch_bounds__(256) void pool_ln2(
    const ushort_t* __restrict__ kin, const ushort_t* __restrict__ vin,
    const float* __restrict__ wkk, const float* __restrict__ wkv,
    const float* __restrict__ gk, const float* __restrict__ bk,
    const float* __restrict__ gv, const float* __restrict__ bv,
    ushort_t* __restrict__ kout, ushort_t* __restrict__ vout)
{
    const int is_k = (blockIdx.y == 0);
    const ushort_t* in = is_k ? kin : vin;
    const float* wk = is_k ? wkk : wkv;
    const float* g  = is_k ? gk : gv;
    const float* b  = is_k ? bk : bv;

    __shared__ float ws_s[27][64];
    const int tid = threadIdx.x;
    for (int e = tid; e < 27 * 64; e += 256) {
        int d = e / 27, tap = e - d * 27;
        ws_s[tap][d] = wk[e];
    }
    __syncthreads();

    const int wave = tid >> 6, lane = tid & 63;
    const int pos = blockIdx.x * 4 + wave;
    if (pos >= NHEAD * N_KEY) return;
    const int head = pos / N_KEY;
    const int idx = pos - head * N_KEY;
    const ushort_t* base = in + (size_t)head * N_Q * HD;

    float val;
    if (idx == 0) {
        val = bf2f(base[lane]);
    } else {
        int p = idx - 1;
        int t1 = p / 196;
        int h1 = (p / 14) % 14;
        int w1 = p % 14;
        val = 0.f;
#pragma unroll
        for (int dt = 0; dt < 3; ++dt) {
            int t = t1 + dt - 1;
            if (t < 0 || t >= 8) continue;
#pragma unroll
            for (int dh = 0; dh < 3; ++dh) {
                int h = 2 * h1 + dh - 1;
                if (h < 0 || h >= 28) continue;
#pragma unroll
                for (int dw = 0; dw < 3; ++dw) {
                    int w = 2 * w1 + dw - 1;
                    if (w < 0 || w >= 28) continue;
                    int n = 1 + (t * 28 + h) * 28 + w;
                    val += bf2f(base[(size_t)n * HD + lane]) * ws_s[(dt * 3 + dh) * 3 + dw][lane];
                }
            }
        }
    }
    float mu = val;
#pragma unroll
    for (int off = 1; off < 64; off <<= 1) mu += __shfl_xor(mu, off, 64);
    mu *= (1.f / 64.f);
    float dv = val - mu;
    float var = dv * dv;
#pragma unroll
    for (int off = 1; off < 64; off <<= 1) var += __shfl_xor(var, off, 64);
    var *= (1.f / 64.f);
    float ln = dv * rsqrtf(var + EPSLN) * g[lane] + b[lane];

    if (!is_k) {
        vout[(size_t)pos * HD + lane] = f2bf(ln);
    } else {
        kout[(size_t)pos * DQH + lane] = f2bf(ln);
        float oh = 0.f;
        if (idx > 0) {
            int p = idx - 1;
            int kt = p / 196, kh = (p / 14) % 14, kw = p % 14;
            if ((lane < 14 && lane == kh) ||
                (lane >= 14 && lane < 28 && (lane - 14) == kw) ||
                (lane >= 28 && lane < 36 && (lane - 28) == kt))
                oh = 1.f;
        }
        kout[(size_t)pos * DQH + 64 + lane] = f2bf(oh);
    }
}

// ---------------------------------------------------------------------------
// Rel-pos dots -> Q-hat cols 64..99. Last block zeroes cls rel channels.
// ---------------------------------------------------------------------------
__global__ __launch_bounds__(256) void rel_dots(
    ushort_t* __restrict__ qhat, const float* __restrict__ rh,
    const float* __restrict__ rw, const float* __restrict__ rt)
{
    const int tid = threadIdx.x;
    if (blockIdx.x == (NHEAD * NSP) / 64) {
        for (int e = tid; e < NHEAD * 64; e += 256) {
            int head = e >> 6, c = e & 63;
            qhat[((size_t)head * N_Q) * DQH + 64 + c] = 0;
        }
        return;
    }

    __shared__ float Rs[125][65];
    for (int e = tid; e < 125 * 64; e += 256) {
        int r = e >> 6, c = e & 63;
        float v = (r < 55) ? rh[r * 64 + c]
                : (r < 110) ? rw[(r - 55) * 64 + c]
                            : rt[(r - 110) * 64 + c];
        Rs[r][c] = v;
    }
    __syncthreads();

    const int wave = tid >> 6, lane = tid & 63;
#pragma unroll 1
    for (int it = 0; it < 16; ++it) {
        int row = blockIdx.x * 64 + wave * 16 + it;
        int head = row / NSP;
        int qs = row - head * NSP;
        ushort_t* qrow = qhat + ((size_t)head * N_Q + 1 + qs) * DQH;
        int t = qs / 784, h = (qs / 28) % 28, w = qs % 28;
        int ridx;
        if (lane < 14)      ridx = h - 2 * lane + 26;
        else if (lane < 28) ridx = 55 + (w - 2 * (lane - 14) + 26);
        else if (lane < 36) ridx = 110 + (t - (lane - 28) + 7);
        else                ridx = 0;

        float s = 0.f;
#pragma unroll
        for (int cq = 0; cq < 8; ++cq) {
            uint2 qv = *(const uint2*)&qrow[cq * 8];
            uint2 qv2 = *(const uint2*)&qrow[cq * 8 + 4];
            const float* Rp = &Rs[ridx][cq * 8];
            s += bflo(qv.x) * Rp[0] + bfhi(qv.x) * Rp[1]
               + bflo(qv.y) * Rp[2] + bfhi(qv.y) * Rp[3]
               + bflo(qv2.x) * Rp[4] + bfhi(qv2.x) * Rp[5]
               + bflo(qv2.y) * Rp[6] + bfhi(qv2.y) * Rp[7];
        }
        if (lane < 36) qrow[64 + lane] = f2bf(s * 8.0f);
    }
}

// ---------------------------------------------------------------------------
// Fused flash attention, swapped-operand, double-buffered single-barrier
// pipeline. Block = (128 q, head), 8 waves x 16 q. P in-register via merged
// butterfly. O^T transposed via LDS bounce (aliased over Ks).
// ---------------------------------------------------------------------------
__global__ __launch_bounds__(512) void attn_mfma(
    const ushort_t* __restrict__ qhat, const ushort_t* __restrict__ khat,
    const ushort_t* __restrict__ vp, ushort_t* __restrict__ aout)
{
    // LDS layout (ushorts): Ks0[0,8192) Ks1[8192,16384) Vt0[16384,20480)
    // Vt1[20480,24576). Epilogue Ob aliases [0, 11264).
    __shared__ ushort_t smem[24576];

    const int tid = threadIdx.x;
    const int wave = tid >> 6, lane = tid & 63;
    const int lo = lane & 15, hi = lane >> 4;
    const int head = blockIdx.y;
    const int q0 = blockIdx.x * 128;
    const int qrow = q0 + wave * 16 + lo;

    // Q-hat fragments (B-operand)
    bf16x8 qa[4];
    if (qrow < N_Q) {
        const ushort_t* qpt = &qhat[((size_t)head * N_Q + qrow) * DQH];
#pragma unroll
        for (int j = 0; j < 4; ++j) qa[j] = *(const bf16x8*)&qpt[j * 32 + hi * 8];
    } else {
#pragma unroll
        for (int j = 0; j < 4; ++j)
#pragma unroll
            for (int e = 0; e < 8; ++e) qa[j][e] = (__bf16)0.0f;
    }

    float m_run = -1e30f, l_run = 0.f;
    f32x4 o[4];
#pragma unroll
    for (int i = 0; i < 4; ++i)
#pragma unroll
        for (int r = 0; r < 4; ++r) o[i][r] = 0.f;

    const bool oddh = (hi & 1) != 0;
    const bool toph = (hi >> 1) != 0;
    const int NT = (N_KEY + 63) / 64;   // 25

    // V staging registers (one uint4 per thread per tile)
    const int vkey = tid & 63, vd0 = (tid >> 6) * 8;
    uint4 vv;

    auto stage = [&](int t) {
        const int m0 = t * 64;
        ushort_t* Ksb = smem + ((t & 1) ? 8192 : 0);
        // K-hat direct to LDS (pre-swizzled source)
#pragma unroll
        for (int i = 0; i < 2; ++i) {
            int ch = wave * 2 + i;              // 1KB chunk 0..15
            int kr = ch * 4 + hi;               // key row 0..63
            int cb = (lo * 16) ^ ((kr & 7) << 4);
            int gm = m0 + kr; if (gm > N_KEY - 1) gm = N_KEY - 1;
            gload_lds16(&khat[((size_t)head * N_KEY + gm) * DQH + (cb >> 1)],
                        &Ksb[ch * 512]);
        }
        // V tile -> regs (written to LDS next iteration)
        int gm = m0 + vkey; if (gm > N_KEY - 1) gm = N_KEY - 1;
        vv = *(const uint4*)&vp[((size_t)head * N_KEY + gm) * HD + vd0];
    };

    stage(0);
    for (int t = 0; t < NT; ++t) {
        const int m0 = t * 64;
        ushort_t* Ksb = smem + ((t & 1) ? 8192 : 0);
        ushort_t* Vtb = smem + 16384 + ((t & 1) ? 4096 : 0);

        // write V regs -> Vt[b] (swizzled)
        {
            ushort_t tmp[8];
            *(uint4*)tmp = vv;
#pragma unroll
            for (int j = 0; j < 8; ++j)
                Vtb[(vd0 + j) * 64 + (vkey ^ (j * 8))] = tmp[j];
        }
        __syncthreads();    // drains gload_lds (Ks[b]) + orders Vt[b] writes
        if (t + 1 < NT) stage(t + 1);   // prefetch next tile into buffer b^1

        // S^T = K-hat @ Q-hat^T : s[sub][reg] = S[key=sub*16+hi*4+reg][q=lo]
        f32x4 s[4];
#pragma unroll
        for (int sub = 0; sub < 4; ++sub)
#pragma unroll
            for (int r = 0; r < 4; ++r) s[sub][r] = 0.f;
#pragma unroll
        for (int kk = 0; kk < 4; ++kk) {
#pragma unroll
            for (int sub = 0; sub < 4; ++sub) {
                int rk = sub * 16 + lo;
                bf16x8 kf = *(const bf16x8*)&Ksb[rk * 128 +
                            ((kk * 32 + hi * 8) ^ ((lo & 7) * 8))];
                s[sub] = __builtin_amdgcn_mfma_f32_16x16x32_bf16(kf, qa[kk], s[sub], 0, 0, 0);
            }
        }

        // tail key mask
        if (m0 + 64 > N_KEY) {
#pragma unroll
            for (int sub = 0; sub < 4; ++sub)
#pragma unroll
                for (int reg = 0; reg < 4; ++reg)
                    if (m0 + sub * 16 + hi * 4 + reg >= N_KEY) s[sub][reg] = -1e30f;
        }

        // scalar online softmax (lane owns one query row)
        float rm = s[0][0];
#pragma unroll
        for (int sub = 0; sub < 4; ++sub)
#pragma unroll
            for (int reg = 0; reg < 4; ++reg) rm = fmaxf(rm, s[sub][reg]);
        rm = fmaxf(rm, __shfl_xor(rm, 16));
        rm = fmaxf(rm, __shfl_xor(rm, 32));

        if (__any(rm - m_run > DEFER_THR)) {
            float mnew = fmaxf(m_run, rm);
            float corr = exp2f(m_run - mnew);
            float ps = 0.f;
#pragma unroll
            for (int sub = 0; sub < 4; ++sub)
#pragma unroll
                for (int reg = 0; reg < 4; ++reg) {
                    float pp = exp2f(s[sub][reg] - mnew);
                    s[sub][reg] = pp; ps += pp;
                }
            ps += __shfl_xor(ps, 16);
            ps += __shfl_xor(ps, 32);
            l_run = l_run * corr + ps;
            m_run = mnew;
#pragma unroll
            for (int i = 0; i < 4; ++i)
#pragma unroll
                for (int r = 0; r < 4; ++r) o[i][r] *= corr;
        } else {
            float ps = 0.f;
#pragma unroll
            for (int sub = 0; sub < 4; ++sub)
#pragma unroll
                for (int reg = 0; reg < 4; ++reg) {
                    float pp = exp2f(s[sub][reg] - m_run);
                    s[sub][reg] = pp; ps += pp;
                }
            ps += __shfl_xor(ps, 16);
            ps += __shfl_xor(ps, 32);
            l_run += ps;
        }

        // P^T pack + merged butterfly -> PV B-frags; O^T += V^T @ P^T
#pragma unroll
        for (int kh2 = 0; kh2 < 2; ++kh2) {
            uint_t x0a = pk2(s[2 * kh2][0], s[2 * kh2][1]);
            uint_t x0b = pk2(s[2 * kh2][2], s[2 * kh2][3]);
            uint_t x1a = pk2(s[2 * kh2 + 1][0], s[2 * kh2 + 1][1]);
            uint_t x1b = pk2(s[2 * kh2 + 1][2], s[2 * kh2 + 1][3]);
            uint_t y0a = __shfl_xor(x0a, 16), y0b = __shfl_xor(x0b, 16);
            uint_t y1a = __shfl_xor(x1a, 16), y1b = __shfl_xor(x1b, 16);
            uint_t c0[4] = { oddh ? y0a : x0a, oddh ? y0b : x0b,
                             oddh ? x0a : y0a, oddh ? x0b : y0b };
            uint_t c1[4] = { oddh ? y1a : x1a, oddh ? y1b : x1b,
                             oddh ? x1a : y1a, oddh ? x1b : y1b };
            union { uint_t u[4]; bf16x8 v; } pw;
#pragma unroll
            for (int i2 = 0; i2 < 4; ++i2) {
                uint_t send = oddh ? c0[i2] : c1[i2];
                uint_t f = __shfl_xor(send, 32);
                pw.u[i2] = (toph != oddh) ? f : (oddh ? c1[i2] : c0[i2]);
            }
#pragma unroll
            for (int sub_d = 0; sub_d < 4; ++sub_d) {
                bf16x8 vf = *(const bf16x8*)&Vtb[(sub_d * 16 + lo) * 64 +
                            ((kh2 * 32 + hi * 8) ^ ((lo & 7) * 8))];
                o[sub_d] = __builtin_amdgcn_mfma_f32_16x16x32_bf16(vf, pw.v, o[sub_d], 0, 0, 0);
            }
        }
    }

    // epilogue: normalize, transpose via LDS bounce (aliases Ks region)
    ushort_t* Ob = smem + wave * (16 * 88);   // [16][88] per wave
    __syncthreads();
    float inv = 1.f / l_run;
#pragma unroll
    for (int sub_d = 0; sub_d < 4; ++sub_d)
#pragma unroll
        for (int reg = 0; reg < 4; ++reg)
            Ob[lo * 88 + sub_d * 16 + hi * 4 + reg] = cvt_native(o[sub_d][reg] * inv);
    __syncthreads();
#pragma unroll
    for (int i = 0; i < 2; ++i) {
        int e = lane + i * 64;
        int r = e >> 3, cc = e & 7;
        int gq = q0 + wave * 16 + r;
        if (gq < N_Q) {
            uint4 ov = *(const uint4*)&Ob[r * 88 + cc * 8];
            *(uint4*)&aout[(size_t)gq * DIMM + head * HD + cc * 8] = ov;
        }
    }
}

// ---------------------------------------------------------------------------
extern "C" void kernel_launch(void* const* d_in, const int* in_sizes, int n_in,
                              void* d_out, int out_size, void* d_ws, size_t ws_size,
                              hipStream_t stream)
{
    const float* x      = (const float*)d_in[0];
    const float* qkv_w  = (const float*)d_in[1];
    const float* qkv_b  = (const float*)d_in[2];
    const float* proj_w = (const float*)d_in[3];
    const float* proj_b = (const float*)d_in[4];
    const float* pkw    = (const float*)d_in[5];
    const float* pvw    = (const float*)d_in[6];
    const float* nkg    = (const float*)d_in[7];
    const float* nkb    = (const float*)d_in[8];
    const float* nvg    = (const float*)d_in[9];
    const float* nvb    = (const float*)d_in[10];
    const float* rph    = (const float*)d_in[11];
    const float* rpw    = (const float*)d_in[12];
    const float* rpt    = (const float*)d_in[13];

    const size_t SZ_X     = (size_t)N_Q * DIMM;
    const size_t SZ_QKVW  = (size_t)3 * DIMM * DIMM;
    const size_t SZ_PROJW = (size_t)DIMM * DIMM;
    const size_t SZ_QHAT  = (size_t)NHEAD * N_Q * DQH;
    const size_t SZ_KV    = (size_t)NHEAD * N_Q * HD;
    const size_t SZ_KHAT  = (size_t)NHEAD * N_KEY * DQH;
    const size_t SZ_VPO   = (size_t)NHEAD * N_KEY * HD;

    ushort_t* xb     = (ushort_t*)d_ws;
    ushort_t* qkvwb  = xb + SZ_X;
    ushort_t* projwb = qkvwb + SZ_QKVW;
    ushort_t* qhat   = projwb + SZ_PROJW;
    ushort_t* kb     = qhat + SZ_QHAT;
    ushort_t* vb     = kb + SZ_KV;
    ushort_t* khat   = vb + SZ_KV;
    ushort_t* vpo    = khat + SZ_KHAT;
    ushort_t* aout   = vpo + SZ_VPO;
    float*    outp   = (float*)d_out;

    // 0) convert inputs to bf16
    cvt3_bf16<<<2048, 256, 0, stream>>>(x, qkv_w, proj_w, xb,
                                        (int)(SZ_X / 8), (int)(SZ_QKVW / 8),
                                        (int)(SZ_PROJW / 8));
    // 1) qkv GEMM: q*QSC -> qhat[:,0:64], k,v -> kb,vb
    gemm_mfma<1><<<dim3(18, 50), 256, 0, stream>>>(xb, qkvwb, qkv_b, N_Q, DIMM,
                                                   nullptr, qhat, kb, vb);
    // 2) pool + LN
    pool_ln2<<<dim3((NHEAD * N_KEY + 3) / 4, 2), 256, 0, stream>>>(
        kb, vb, pkw, pvw, nkg, nkb, nvg, nvb, khat, vpo);
    // 3) rel-pos dots (+ cls fix)
    rel_dots<<<dim3((NHEAD * NSP) / 64 + 1), 256, 0, stream>>>(qhat, rph, rpw, rpt);
    // 4) fused attention (pipelined, 128-q blocks, 8 waves)
    attn_mfma<<<dim3((N_Q + 127) / 128, NHEAD), 512, 0, stream>>>(
        qhat, khat, vpo, aout);
    // 5) proj GEMM
    gemm_mfma<0><<<dim3(6, 50), 256, 0, stream>>>(aout, projwb, proj_b, N_Q, DIMM,
                                                  outp, nullptr, nullptr, nullptr);
}